// Round 4
// baseline (650.934 us; speedup 1.0000x reference)
//
#include <hip/hip_runtime.h>
#include <math.h>

// GATNet: N=100000 nodes, D=128, HEADS=4, HID=32, OUT_C=64, E=1.6M (+N self-loops)
#define NEG_SLOPE 0.2f

__device__ __forceinline__ float leaky(float x) { return x > 0.f ? x : NEG_SLOPE * x; }

// ---------------- CSR build ----------------

__global__ void zero_kernel(int* __restrict__ p, int n) {
    int i = blockIdx.x * blockDim.x + threadIdx.x;
    if (i < n) p[i] = 0;
}

__global__ void hist_kernel(const int* __restrict__ ei, int E, int E2, int* __restrict__ counts) {
    int e = blockIdx.x * blockDim.x + threadIdx.x;
    if (e >= E2) return;
    int dst = (e < E) ? ei[E + e] : (e - E);   // self-loop tail
    atomicAdd(&counts[dst], 1);
}

// per-256-chunk exclusive scan; chunk totals to bs[]
__global__ void scan1_kernel(const int* __restrict__ counts, int N,
                             int* __restrict__ indptr, int* __restrict__ bs) {
    __shared__ int s[256];
    int t = threadIdx.x;
    int i = blockIdx.x * 256 + t;
    int v = (i < N) ? counts[i] : 0;
    s[t] = v;
    __syncthreads();
    for (int off = 1; off < 256; off <<= 1) {
        int u = (t >= off) ? s[t - off] : 0;
        __syncthreads();
        s[t] += u;
        __syncthreads();
    }
    if (i < N) indptr[i] = s[t] - v;      // exclusive within chunk
    if (t == 255) bs[blockIdx.x] = s[255]; // chunk total
}

// single-block exclusive scan of chunk totals (B <= 512)
__global__ void scan2_kernel(int* __restrict__ bs, int B) {
    __shared__ int s[512];
    int t = threadIdx.x;
    s[t] = (t < B) ? bs[t] : 0;
    __syncthreads();
    for (int off = 1; off < 512; off <<= 1) {
        int u = (t >= off) ? s[t - off] : 0;
        __syncthreads();
        s[t] += u;
        __syncthreads();
    }
    if (t < B) bs[t] = (t == 0) ? 0 : s[t - 1];
}

__global__ void scan3_kernel(int* __restrict__ indptr, int* __restrict__ cursor,
                             const int* __restrict__ bs, int N) {
    int i = blockIdx.x * blockDim.x + threadIdx.x;
    if (i >= N) return;
    int v = indptr[i] + bs[i >> 8];
    indptr[i] = v;
    cursor[i] = v;
}

__global__ void scatter_kernel(const int* __restrict__ ei, int E, int E2,
                               int* __restrict__ cursor, int* __restrict__ csr_src) {
    int e = blockIdx.x * blockDim.x + threadIdx.x;
    if (e >= E2) return;
    int src, dst;
    if (e < E) { src = ei[e]; dst = ei[E + e]; }
    else       { src = e - E; dst = e - E; }
    int pos = atomicAdd(&cursor[dst], 1);
    csr_src[pos] = src;
}

// ---------------- register-tiled fp32 GEMMs ----------------

__global__ __launch_bounds__(256) void gemm1_kernel(const float* __restrict__ emb,
                             const int* __restrict__ xidx,
                             const float* __restrict__ W1, float* __restrict__ h1, int N) {
    __shared__ float xs[64][128];
    __shared__ float ws[128][64];
    int tid = threadIdx.x;
    int r0 = blockIdx.x * 64;
    int c0 = blockIdx.y * 64;
    {   // stage W1 cols [c0, c0+64)
        const float4* W4 = (const float4*)W1;   // row stride 32 float4
        float4* ws4 = (float4*)ws;              // row stride 16 float4
        int cbase = c0 >> 2;
        for (int i = tid; i < 128 * 16; i += 256) {
            int k = i >> 4, c = i & 15;
            ws4[i] = W4[k * 32 + cbase + c];
        }
    }
    {   // stage x rows [r0, r0+64) with embedding gather
        float4* xs4 = (float4*)xs;
        for (int i = tid; i < 64 * 32; i += 256) {
            int r = i >> 5, c = i & 31;
            int row = r0 + r;
            float4 v = make_float4(0.f, 0.f, 0.f, 0.f);
            if (row < N) {
                int s = xidx[row];
                v = ((const float4*)emb)[(size_t)s * 32 + c];
            }
            xs4[i] = v;
        }
    }
    __syncthreads();
    int tr = tid >> 4;   // 0..15 -> rows tr*4..tr*4+3
    int tc = tid & 15;   // 0..15 -> cols tc*4..tc*4+3
    float4 acc[4];
    acc[0] = acc[1] = acc[2] = acc[3] = make_float4(0.f, 0.f, 0.f, 0.f);
    for (int k = 0; k < 128; k += 4) {
        float4 wv0 = *(const float4*)&ws[k][tc * 4];
        float4 wv1 = *(const float4*)&ws[k + 1][tc * 4];
        float4 wv2 = *(const float4*)&ws[k + 2][tc * 4];
        float4 wv3 = *(const float4*)&ws[k + 3][tc * 4];
#pragma unroll
        for (int i = 0; i < 4; i++) {
            float4 xv = *(const float4*)&xs[tr * 4 + i][k];
            acc[i].x = fmaf(xv.x, wv0.x, acc[i].x);
            acc[i].y = fmaf(xv.x, wv0.y, acc[i].y);
            acc[i].z = fmaf(xv.x, wv0.z, acc[i].z);
            acc[i].w = fmaf(xv.x, wv0.w, acc[i].w);
            acc[i].x = fmaf(xv.y, wv1.x, acc[i].x);
            acc[i].y = fmaf(xv.y, wv1.y, acc[i].y);
            acc[i].z = fmaf(xv.y, wv1.z, acc[i].z);
            acc[i].w = fmaf(xv.y, wv1.w, acc[i].w);
            acc[i].x = fmaf(xv.z, wv2.x, acc[i].x);
            acc[i].y = fmaf(xv.z, wv2.y, acc[i].y);
            acc[i].z = fmaf(xv.z, wv2.z, acc[i].z);
            acc[i].w = fmaf(xv.z, wv2.w, acc[i].w);
            acc[i].x = fmaf(xv.w, wv3.x, acc[i].x);
            acc[i].y = fmaf(xv.w, wv3.y, acc[i].y);
            acc[i].z = fmaf(xv.w, wv3.z, acc[i].z);
            acc[i].w = fmaf(xv.w, wv3.w, acc[i].w);
        }
    }
#pragma unroll
    for (int i = 0; i < 4; i++) {
        int row = r0 + tr * 4 + i;
        if (row < N) *(float4*)&h1[(size_t)row * 128 + c0 + tc * 4] = acc[i];
    }
}

__global__ __launch_bounds__(256) void gemm2_kernel(const float* __restrict__ x1,
                             const float* __restrict__ W2,
                             float* __restrict__ h2, int N) {
    __shared__ float xs[64][128];
    __shared__ float ws[128][64];
    int tid = threadIdx.x;
    int r0 = blockIdx.x * 64;
    {   // stage all of W2
        const float4* W4 = (const float4*)W2;
        float4* ws4 = (float4*)ws;
        for (int i = tid; i < 128 * 16; i += 256) ws4[i] = W4[i];
    }
    {   // stage x rows
        float4* xs4 = (float4*)xs;
        for (int i = tid; i < 64 * 32; i += 256) {
            int r = i >> 5, c = i & 31;
            int row = r0 + r;
            float4 v = make_float4(0.f, 0.f, 0.f, 0.f);
            if (row < N) v = ((const float4*)x1)[(size_t)row * 32 + c];
            xs4[i] = v;
        }
    }
    __syncthreads();
    int tr = tid >> 4;
    int tc = tid & 15;
    float4 acc[4];
    acc[0] = acc[1] = acc[2] = acc[3] = make_float4(0.f, 0.f, 0.f, 0.f);
    for (int k = 0; k < 128; k += 4) {
        float4 wv0 = *(const float4*)&ws[k][tc * 4];
        float4 wv1 = *(const float4*)&ws[k + 1][tc * 4];
        float4 wv2 = *(const float4*)&ws[k + 2][tc * 4];
        float4 wv3 = *(const float4*)&ws[k + 3][tc * 4];
#pragma unroll
        for (int i = 0; i < 4; i++) {
            float4 xv = *(const float4*)&xs[tr * 4 + i][k];
            acc[i].x = fmaf(xv.x, wv0.x, acc[i].x);
            acc[i].y = fmaf(xv.x, wv0.y, acc[i].y);
            acc[i].z = fmaf(xv.x, wv0.z, acc[i].z);
            acc[i].w = fmaf(xv.x, wv0.w, acc[i].w);
            acc[i].x = fmaf(xv.y, wv1.x, acc[i].x);
            acc[i].y = fmaf(xv.y, wv1.y, acc[i].y);
            acc[i].z = fmaf(xv.y, wv1.z, acc[i].z);
            acc[i].w = fmaf(xv.y, wv1.w, acc[i].w);
            acc[i].x = fmaf(xv.z, wv2.x, acc[i].x);
            acc[i].y = fmaf(xv.z, wv2.y, acc[i].y);
            acc[i].z = fmaf(xv.z, wv2.z, acc[i].z);
            acc[i].w = fmaf(xv.z, wv2.w, acc[i].w);
            acc[i].x = fmaf(xv.w, wv3.x, acc[i].x);
            acc[i].y = fmaf(xv.w, wv3.y, acc[i].y);
            acc[i].z = fmaf(xv.w, wv3.z, acc[i].z);
            acc[i].w = fmaf(xv.w, wv3.w, acc[i].w);
        }
    }
#pragma unroll
    for (int i = 0; i < 4; i++) {
        int row = r0 + tr * 4 + i;
        if (row < N) *(float4*)&h2[(size_t)row * 64 + tc * 4] = acc[i];
    }
}

// ---------------- attention logits ----------------

__global__ void alpha1_kernel(const float* __restrict__ h1, const float* __restrict__ aw,
                              const float* __restrict__ dw, float* __restrict__ as1,
                              float* __restrict__ ad1, int N) {
    int t = blockIdx.x * blockDim.x + threadIdx.x;
    if (t >= N * 4) return;
    int n = t >> 2, h = t & 3;
    const float4* hp = (const float4*)(h1 + (size_t)n * 128 + h * 32);
    const float4* ap = (const float4*)(aw + h * 32);
    const float4* dp = (const float4*)(dw + h * 32);
    float s = 0.f, d = 0.f;
#pragma unroll
    for (int j = 0; j < 8; j++) {
        float4 v = hp[j], a = ap[j], dd = dp[j];
        s += v.x * a.x + v.y * a.y + v.z * a.z + v.w * a.w;
        d += v.x * dd.x + v.y * dd.y + v.z * dd.z + v.w * dd.w;
    }
    as1[t] = s;
    ad1[t] = d;
}

__global__ void alpha2_kernel(const float* __restrict__ h2, const float* __restrict__ aw,
                              const float* __restrict__ dw, float* __restrict__ as2,
                              float* __restrict__ ad2, int N) {
    int n = blockIdx.x * blockDim.x + threadIdx.x;
    if (n >= N) return;
    const float4* hp = (const float4*)(h2 + (size_t)n * 64);
    float s = 0.f, d = 0.f;
#pragma unroll
    for (int j = 0; j < 16; j++) {
        float4 v = hp[j];
        float4 a = ((const float4*)aw)[j];
        float4 dd = ((const float4*)dw)[j];
        s += v.x * a.x + v.y * a.y + v.z * a.z + v.w * a.w;
        d += v.x * dd.x + v.y * dd.y + v.z * dd.z + v.w * dd.w;
    }
    as2[n] = s;
    ad2[n] = d;
}

// ---------------- aggregation: wave-per-node register softmax ----------------
// One wave per dst node (4 nodes / 256-thread block). Lane i owns edge i
// (deg<=64 fast path; chunked generic path for larger). No LDS, no barriers.

__global__ void __launch_bounds__(256)
agg1_kernel(const int* __restrict__ csr, const int* __restrict__ indptr,
            const int* __restrict__ counts, const float* __restrict__ as1,
            const float* __restrict__ ad1, const float* __restrict__ h1,
            const float* __restrict__ b1, float* __restrict__ x1, int N) {
    int lane = threadIdx.x & 63;
    int n = blockIdx.x * 4 + (threadIdx.x >> 6);
    if (n >= N) return;
    int start = indptr[n];
    int cnt = counts[n];
    float4 ad4 = ((const float4*)ad1)[n];

    // chunk 0: lane i -> edge i
    int src0 = 0;
    float4 e0 = make_float4(-1e30f, -1e30f, -1e30f, -1e30f);
    if (lane < cnt) {
        src0 = csr[start + lane];
        float4 a = ((const float4*)as1)[src0];
        e0.x = leaky(a.x + ad4.x);
        e0.y = leaky(a.y + ad4.y);
        e0.z = leaky(a.z + ad4.z);
        e0.w = leaky(a.w + ad4.w);
    }
    // wave max
    float4 m4 = e0;
#pragma unroll
    for (int off = 32; off >= 1; off >>= 1) {
        m4.x = fmaxf(m4.x, __shfl_xor(m4.x, off));
        m4.y = fmaxf(m4.y, __shfl_xor(m4.y, off));
        m4.z = fmaxf(m4.z, __shfl_xor(m4.z, off));
        m4.w = fmaxf(m4.w, __shfl_xor(m4.w, off));
    }
    if (cnt > 64) {   // rare: merge extra chunk maxes
        for (int base = 64; base < cnt; base += 64) {
            float4 e = make_float4(-1e30f, -1e30f, -1e30f, -1e30f);
            if (base + lane < cnt) {
                int s = csr[start + base + lane];
                float4 a = ((const float4*)as1)[s];
                e.x = leaky(a.x + ad4.x); e.y = leaky(a.y + ad4.y);
                e.z = leaky(a.z + ad4.z); e.w = leaky(a.w + ad4.w);
            }
#pragma unroll
            for (int off = 32; off >= 1; off >>= 1) {
                e.x = fmaxf(e.x, __shfl_xor(e.x, off));
                e.y = fmaxf(e.y, __shfl_xor(e.y, off));
                e.z = fmaxf(e.z, __shfl_xor(e.z, off));
                e.w = fmaxf(e.w, __shfl_xor(e.w, off));
            }
            m4.x = fmaxf(m4.x, e.x); m4.y = fmaxf(m4.y, e.y);
            m4.z = fmaxf(m4.z, e.z); m4.w = fmaxf(m4.w, e.w);
        }
    }
    // exp + wave sum (inactive lanes: exp(-1e30-m)=0)
    float4 p0;
    p0.x = __expf(e0.x - m4.x);
    p0.y = __expf(e0.y - m4.y);
    p0.z = __expf(e0.z - m4.z);
    p0.w = __expf(e0.w - m4.w);
    float4 l4 = p0;
#pragma unroll
    for (int off = 32; off >= 1; off >>= 1) {
        l4.x += __shfl_xor(l4.x, off);
        l4.y += __shfl_xor(l4.y, off);
        l4.z += __shfl_xor(l4.z, off);
        l4.w += __shfl_xor(l4.w, off);
    }
    if (cnt > 64) {
        for (int base = 64; base < cnt; base += 64) {
            float4 p = make_float4(0.f, 0.f, 0.f, 0.f);
            if (base + lane < cnt) {
                int s = csr[start + base + lane];
                float4 a = ((const float4*)as1)[s];
                p.x = __expf(leaky(a.x + ad4.x) - m4.x);
                p.y = __expf(leaky(a.y + ad4.y) - m4.y);
                p.z = __expf(leaky(a.z + ad4.z) - m4.z);
                p.w = __expf(leaky(a.w + ad4.w) - m4.w);
            }
#pragma unroll
            for (int off = 32; off >= 1; off >>= 1) {
                p.x += __shfl_xor(p.x, off);
                p.y += __shfl_xor(p.y, off);
                p.z += __shfl_xor(p.z, off);
                p.w += __shfl_xor(p.w, off);
            }
            l4.x += p.x; l4.y += p.y; l4.z += p.z; l4.w += p.w;
        }
    }
    float4 li = make_float4(1.f / l4.x, 1.f / l4.y, 1.f / l4.z, 1.f / l4.w);
    float4 w0 = make_float4(p0.x * li.x, p0.y * li.y, p0.z * li.z, p0.w * li.w);

    // phase B: lane owns channel pair c = lane*2 (head = lane>>4)
    int h = lane >> 4;
    const float2* h1v = (const float2*)h1;
    float ax = 0.f, ay = 0.f;
    int nn = min(cnt, 64);
    int j = 0;
    for (; j + 4 <= nn; j += 4) {
        int s0 = __shfl(src0, j),     s1 = __shfl(src0, j + 1);
        int s2 = __shfl(src0, j + 2), s3 = __shfl(src0, j + 3);
        float wx0 = __shfl(w0.x, j), wy0 = __shfl(w0.y, j), wz0 = __shfl(w0.z, j), ww0 = __shfl(w0.w, j);
        float wx1 = __shfl(w0.x, j+1), wy1 = __shfl(w0.y, j+1), wz1 = __shfl(w0.z, j+1), ww1 = __shfl(w0.w, j+1);
        float wx2 = __shfl(w0.x, j+2), wy2 = __shfl(w0.y, j+2), wz2 = __shfl(w0.z, j+2), ww2 = __shfl(w0.w, j+2);
        float wx3 = __shfl(w0.x, j+3), wy3 = __shfl(w0.y, j+3), wz3 = __shfl(w0.z, j+3), ww3 = __shfl(w0.w, j+3);
        float2 v0 = h1v[(size_t)s0 * 64 + lane];
        float2 v1 = h1v[(size_t)s1 * 64 + lane];
        float2 v2 = h1v[(size_t)s2 * 64 + lane];
        float2 v3 = h1v[(size_t)s3 * 64 + lane];
        float w_0 = (h < 2) ? ((h == 0) ? wx0 : wy0) : ((h == 2) ? wz0 : ww0);
        float w_1 = (h < 2) ? ((h == 0) ? wx1 : wy1) : ((h == 2) ? wz1 : ww1);
        float w_2 = (h < 2) ? ((h == 0) ? wx2 : wy2) : ((h == 2) ? wz2 : ww2);
        float w_3 = (h < 2) ? ((h == 0) ? wx3 : wy3) : ((h == 2) ? wz3 : ww3);
        ax = fmaf(w_0, v0.x, ax); ay = fmaf(w_0, v0.y, ay);
        ax = fmaf(w_1, v1.x, ax); ay = fmaf(w_1, v1.y, ay);
        ax = fmaf(w_2, v2.x, ax); ay = fmaf(w_2, v2.y, ay);
        ax = fmaf(w_3, v3.x, ax); ay = fmaf(w_3, v3.y, ay);
    }
    for (; j < nn; j++) {
        int s = __shfl(src0, j);
        float wx = __shfl(w0.x, j), wy = __shfl(w0.y, j), wz = __shfl(w0.z, j), ww = __shfl(w0.w, j);
        float w = (h < 2) ? ((h == 0) ? wx : wy) : ((h == 2) ? wz : ww);
        float2 v = h1v[(size_t)s * 64 + lane];
        ax = fmaf(w, v.x, ax); ay = fmaf(w, v.y, ay);
    }
    if (cnt > 64) {
        for (int base = 64; base < cnt; base += 64) {
            int srcc = 0;
            float4 wc = make_float4(0.f, 0.f, 0.f, 0.f);
            if (base + lane < cnt) {
                srcc = csr[start + base + lane];
                float4 a = ((const float4*)as1)[srcc];
                wc.x = __expf(leaky(a.x + ad4.x) - m4.x) * li.x;
                wc.y = __expf(leaky(a.y + ad4.y) - m4.y) * li.y;
                wc.z = __expf(leaky(a.z + ad4.z) - m4.z) * li.z;
                wc.w = __expf(leaky(a.w + ad4.w) - m4.w) * li.w;
            }
            int mm = min(cnt - base, 64);
            for (int k = 0; k < mm; k++) {
                int s = __shfl(srcc, k);
                float wx = __shfl(wc.x, k), wy = __shfl(wc.y, k), wz = __shfl(wc.z, k), ww = __shfl(wc.w, k);
                float w = (h < 2) ? ((h == 0) ? wx : wy) : ((h == 2) ? wz : ww);
                float2 v = h1v[(size_t)s * 64 + lane];
                ax = fmaf(w, v.x, ax); ay = fmaf(w, v.y, ay);
            }
        }
    }
    float2 b = ((const float2*)b1)[lane];
    float ox = ax + b.x, oy = ay + b.y;
    ox = (ox > 0.f) ? ox : (__expf(ox) - 1.f);   // ELU
    oy = (oy > 0.f) ? oy : (__expf(oy) - 1.f);
    ((float2*)x1)[(size_t)n * 64 + lane] = make_float2(ox, oy);
}

__global__ void __launch_bounds__(256)
agg2_kernel(const int* __restrict__ csr, const int* __restrict__ indptr,
            const int* __restrict__ counts, const float* __restrict__ as2,
            const float* __restrict__ ad2, const float* __restrict__ h2,
            const float* __restrict__ b2, float* __restrict__ out, int N) {
    int lane = threadIdx.x & 63;
    int n = blockIdx.x * 4 + (threadIdx.x >> 6);
    if (n >= N) return;
    int start = indptr[n];
    int cnt = counts[n];
    float ad = ad2[n];

    int src0 = 0;
    float e0 = -1e30f;
    if (lane < cnt) {
        src0 = csr[start + lane];
        e0 = leaky(as2[src0] + ad);
    }
    float m = e0;
#pragma unroll
    for (int off = 32; off >= 1; off >>= 1) m = fmaxf(m, __shfl_xor(m, off));
    if (cnt > 64) {
        for (int base = 64; base < cnt; base += 64) {
            float e = -1e30f;
            if (base + lane < cnt) e = leaky(as2[csr[start + base + lane]] + ad);
#pragma unroll
            for (int off = 32; off >= 1; off >>= 1) e = fmaxf(e, __shfl_xor(e, off));
            m = fmaxf(m, e);
        }
    }
    float p0 = __expf(e0 - m);
    float l = p0;
#pragma unroll
    for (int off = 32; off >= 1; off >>= 1) l += __shfl_xor(l, off);
    if (cnt > 64) {
        for (int base = 64; base < cnt; base += 64) {
            float p = 0.f;
            if (base + lane < cnt) p = __expf(leaky(as2[csr[start + base + lane]] + ad) - m);
#pragma unroll
            for (int off = 32; off >= 1; off >>= 1) p += __shfl_xor(p, off);
            l += p;
        }
    }
    float li = 1.f / l;
    float w0 = p0 * li;

    float acc = 0.f;
    int nn = min(cnt, 64);
    int j = 0;
    for (; j + 4 <= nn; j += 4) {
        int s0 = __shfl(src0, j),     s1 = __shfl(src0, j + 1);
        int s2 = __shfl(src0, j + 2), s3 = __shfl(src0, j + 3);
        float w_0 = __shfl(w0, j),     w_1 = __shfl(w0, j + 1);
        float w_2 = __shfl(w0, j + 2), w_3 = __shfl(w0, j + 3);
        float v0 = h2[(size_t)s0 * 64 + lane];
        float v1 = h2[(size_t)s1 * 64 + lane];
        float v2 = h2[(size_t)s2 * 64 + lane];
        float v3 = h2[(size_t)s3 * 64 + lane];
        acc = fmaf(w_0, v0, acc);
        acc = fmaf(w_1, v1, acc);
        acc = fmaf(w_2, v2, acc);
        acc = fmaf(w_3, v3, acc);
    }
    for (; j < nn; j++) {
        acc = fmaf(__shfl(w0, j), h2[(size_t)__shfl(src0, j) * 64 + lane], acc);
    }
    if (cnt > 64) {
        for (int base = 64; base < cnt; base += 64) {
            int srcc = 0;
            float wc = 0.f;
            if (base + lane < cnt) {
                srcc = csr[start + base + lane];
                wc = __expf(leaky(as2[srcc] + ad) - m) * li;
            }
            int mm = min(cnt - base, 64);
            for (int k = 0; k < mm; k++) {
                acc = fmaf(__shfl(wc, k), h2[(size_t)__shfl(srcc, k) * 64 + lane], acc);
            }
        }
    }
    out[(size_t)n * 64 + lane] = acc + b2[lane];
}

// ---------------- launcher ----------------

extern "C" void kernel_launch(void* const* d_in, const int* in_sizes, int n_in,
                              void* d_out, int out_size, void* d_ws, size_t ws_size,
                              hipStream_t stream) {
    const int*   xidx = (const int*)d_in[0];
    const int*   ei   = (const int*)d_in[1];
    const float* emb  = (const float*)d_in[2];
    const float* W1   = (const float*)d_in[3];
    const float* a_s1 = (const float*)d_in[4];
    const float* a_d1 = (const float*)d_in[5];
    const float* b1   = (const float*)d_in[6];
    const float* W2   = (const float*)d_in[7];
    const float* a_s2 = (const float*)d_in[8];
    const float* a_d2 = (const float*)d_in[9];
    const float* b2   = (const float*)d_in[10];
    float* out = (float*)d_out;

    const int N  = in_sizes[0];
    const int E  = in_sizes[1] / 2;
    const int E2 = E + N;
    const int B  = (N + 255) / 256;   // scan chunks (391 for N=100000)

    // workspace layout
    int* ws_i   = (int*)d_ws;
    int* counts = ws_i;
    int* indptr = ws_i + N;
    int* cursor = ws_i + 2 * (size_t)N;
    int* bs     = ws_i + 3 * (size_t)N;
    int* csr    = ws_i + 3 * (size_t)N + 512;
    size_t fbase = ((size_t)(3 * (size_t)N + 512 + E2) + 3) & ~(size_t)3;
    float* ws_f = (float*)d_ws;
    float* h1  = ws_f + fbase;                  // N*128
    float* x1  = h1 + (size_t)N * 128;          // N*128
    float* as1 = x1 + (size_t)N * 128;          // N*4
    float* ad1 = as1 + (size_t)N * 4;           // N*4
    float* h2  = h1;   // alias: h1 dead after agg1
    float* as2 = as1;  // alias: as1 dead after agg1
    float* ad2 = ad1;

    // CSR build
    zero_kernel<<<(N + 255) / 256, 256, 0, stream>>>(counts, N);
    hist_kernel<<<(E2 + 255) / 256, 256, 0, stream>>>(ei, E, E2, counts);
    scan1_kernel<<<B, 256, 0, stream>>>(counts, N, indptr, bs);
    scan2_kernel<<<1, 512, 0, stream>>>(bs, B);
    scan3_kernel<<<(N + 255) / 256, 256, 0, stream>>>(indptr, cursor, bs, N);
    scatter_kernel<<<(E2 + 255) / 256, 256, 0, stream>>>(ei, E, E2, cursor, csr);

    // Layer 1
    {
        dim3 g((N + 63) / 64, 2);
        gemm1_kernel<<<g, 256, 0, stream>>>(emb, xidx, W1, h1, N);
    }
    alpha1_kernel<<<(N * 4 + 255) / 256, 256, 0, stream>>>(h1, a_s1, a_d1, as1, ad1, N);
    agg1_kernel<<<(N + 3) / 4, 256, 0, stream>>>(csr, indptr, counts, as1, ad1, h1, b1, x1, N);

    // Layer 2
    gemm2_kernel<<<(N + 63) / 64, 256, 0, stream>>>(x1, W2, h2, N);
    alpha2_kernel<<<(N + 255) / 256, 256, 0, stream>>>(h2, a_s2, a_d2, as2, ad2, N);
    agg2_kernel<<<(N + 3) / 4, 256, 0, stream>>>(csr, indptr, counts, as2, ad2, h2, b2, out, N);
}

// Round 5
// 632.556 us; speedup vs baseline: 1.0291x; 1.0291x over previous
//
#include <hip/hip_runtime.h>
#include <math.h>

// GATNet: N=100000 nodes, D=128, HEADS=4, HID=32, OUT_C=64, E=1.6M (+N self-loops)
#define NEG_SLOPE 0.2f

__device__ __forceinline__ float leaky(float x) { return x > 0.f ? x : NEG_SLOPE * x; }
__device__ __forceinline__ float dot4(float4 a, float4 b) {
    return a.x * b.x + a.y * b.y + a.z * b.z + a.w * b.w;
}
// fp32 -> bf16 round-to-nearest-even
__device__ __forceinline__ unsigned short f2bf(float f) {
    unsigned int x = __float_as_uint(f);
    unsigned int r = (x + 0x7fffu + ((x >> 16) & 1u)) >> 16;
    return (unsigned short)r;
}

// ---------------- CSR build ----------------

__global__ void zero_kernel(int* __restrict__ p, int n) {
    int i = blockIdx.x * blockDim.x + threadIdx.x;
    if (i < n) p[i] = 0;
}

__global__ void hist_kernel(const int* __restrict__ ei, int E, int E2, int* __restrict__ counts) {
    int e = blockIdx.x * blockDim.x + threadIdx.x;
    if (e >= E2) return;
    int dst = (e < E) ? ei[E + e] : (e - E);   // self-loop tail
    atomicAdd(&counts[dst], 1);
}

__global__ void scan1_kernel(const int* __restrict__ counts, int N,
                             int* __restrict__ indptr, int* __restrict__ bs) {
    __shared__ int s[256];
    int t = threadIdx.x;
    int i = blockIdx.x * 256 + t;
    int v = (i < N) ? counts[i] : 0;
    s[t] = v;
    __syncthreads();
    for (int off = 1; off < 256; off <<= 1) {
        int u = (t >= off) ? s[t - off] : 0;
        __syncthreads();
        s[t] += u;
        __syncthreads();
    }
    if (i < N) indptr[i] = s[t] - v;
    if (t == 255) bs[blockIdx.x] = s[255];
}

__global__ void scan2_kernel(int* __restrict__ bs, int B) {
    __shared__ int s[512];
    int t = threadIdx.x;
    s[t] = (t < B) ? bs[t] : 0;
    __syncthreads();
    for (int off = 1; off < 512; off <<= 1) {
        int u = (t >= off) ? s[t - off] : 0;
        __syncthreads();
        s[t] += u;
        __syncthreads();
    }
    if (t < B) bs[t] = (t == 0) ? 0 : s[t - 1];
}

__global__ void scan3_kernel(int* __restrict__ indptr, int* __restrict__ cursor,
                             const int* __restrict__ bs, int N) {
    int i = blockIdx.x * blockDim.x + threadIdx.x;
    if (i >= N) return;
    int v = indptr[i] + bs[i >> 8];
    indptr[i] = v;
    cursor[i] = v;
}

__global__ void scatter_kernel(const int* __restrict__ ei, int E, int E2,
                               int* __restrict__ cursor, int* __restrict__ csr_src) {
    int e = blockIdx.x * blockDim.x + threadIdx.x;
    if (e >= E2) return;
    int src, dst;
    if (e < E) { src = ei[e]; dst = ei[E + e]; }
    else       { src = e - E; dst = e - E; }
    int pos = atomicAdd(&cursor[dst], 1);
    csr_src[pos] = src;
}

// ---------------- gemm1 + fused alpha1, bf16 h1 output ----------------
// Block = 64 rows x 64 cols (gridDim.y=2 col halves), 256 threads, 4x4/thread.
// Epilogue: h1 stored ONLY as bf16; as1/ad1 computed from fp32 accs via
// 8-lane shfl reduction (each 64-col half holds exactly 2 whole heads).

__global__ __launch_bounds__(256) void gemm1_kernel(const float* __restrict__ emb,
                             const int* __restrict__ xidx,
                             const float* __restrict__ W1,
                             unsigned short* __restrict__ h1b,
                             const float* __restrict__ a_s1, const float* __restrict__ a_d1,
                             float* __restrict__ as1, float* __restrict__ ad1, int N) {
    __shared__ float xs[64][128];
    __shared__ float ws[128][64];
    int tid = threadIdx.x;
    int r0 = blockIdx.x * 64;
    int c0 = blockIdx.y * 64;
    {   // stage W1 cols [c0, c0+64)
        const float4* W4 = (const float4*)W1;
        float4* ws4 = (float4*)ws;
        int cbase = c0 >> 2;
        for (int i = tid; i < 128 * 16; i += 256) {
            int k = i >> 4, c = i & 15;
            ws4[i] = W4[k * 32 + cbase + c];
        }
    }
    {   // stage x rows [r0, r0+64) (xidx gather)
        float4* xs4 = (float4*)xs;
        for (int i = tid; i < 64 * 32; i += 256) {
            int r = i >> 5, c = i & 31;
            int row = r0 + r;
            float4 v = make_float4(0.f, 0.f, 0.f, 0.f);
            if (row < N) {
                int s = xidx[row];
                v = ((const float4*)emb)[(size_t)s * 32 + c];
            }
            xs4[i] = v;
        }
    }
    __syncthreads();
    int tr = tid >> 4;
    int tc = tid & 15;
    float4 acc[4];
    acc[0] = acc[1] = acc[2] = acc[3] = make_float4(0.f, 0.f, 0.f, 0.f);
    for (int k = 0; k < 128; k += 4) {
        float4 wv0 = *(const float4*)&ws[k][tc * 4];
        float4 wv1 = *(const float4*)&ws[k + 1][tc * 4];
        float4 wv2 = *(const float4*)&ws[k + 2][tc * 4];
        float4 wv3 = *(const float4*)&ws[k + 3][tc * 4];
#pragma unroll
        for (int i = 0; i < 4; i++) {
            float4 xv = *(const float4*)&xs[tr * 4 + i][k];
            acc[i].x = fmaf(xv.x, wv0.x, acc[i].x);
            acc[i].y = fmaf(xv.x, wv0.y, acc[i].y);
            acc[i].z = fmaf(xv.x, wv0.z, acc[i].z);
            acc[i].w = fmaf(xv.x, wv0.w, acc[i].w);
            acc[i].x = fmaf(xv.y, wv1.x, acc[i].x);
            acc[i].y = fmaf(xv.y, wv1.y, acc[i].y);
            acc[i].z = fmaf(xv.y, wv1.z, acc[i].z);
            acc[i].w = fmaf(xv.y, wv1.w, acc[i].w);
            acc[i].x = fmaf(xv.z, wv2.x, acc[i].x);
            acc[i].y = fmaf(xv.z, wv2.y, acc[i].y);
            acc[i].z = fmaf(xv.z, wv2.z, acc[i].z);
            acc[i].w = fmaf(xv.z, wv2.w, acc[i].w);
            acc[i].x = fmaf(xv.w, wv3.x, acc[i].x);
            acc[i].y = fmaf(xv.w, wv3.y, acc[i].y);
            acc[i].z = fmaf(xv.w, wv3.z, acc[i].z);
            acc[i].w = fmaf(xv.w, wv3.w, acc[i].w);
        }
    }
    // epilogue: bf16 h1 + fused alpha1
    int colbase = c0 + tc * 4;
    int h = colbase >> 5;          // global head (this 64-col half holds 2 heads)
    int off = colbase & 31;
    float4 av = *(const float4*)&a_s1[h * 32 + off];
    float4 dv = *(const float4*)&a_d1[h * 32 + off];
#pragma unroll
    for (int i = 0; i < 4; i++) {
        int row = r0 + tr * 4 + i;
        if (row < N) {
            ushort4 pk;
            pk.x = f2bf(acc[i].x); pk.y = f2bf(acc[i].y);
            pk.z = f2bf(acc[i].z); pk.w = f2bf(acc[i].w);
            *(ushort4*)&h1b[(size_t)row * 128 + colbase] = pk;
        }
        float ps = dot4(acc[i], av);
        float pd = dot4(acc[i], dv);
        ps += __shfl_xor(ps, 1); pd += __shfl_xor(pd, 1);
        ps += __shfl_xor(ps, 2); pd += __shfl_xor(pd, 2);
        ps += __shfl_xor(ps, 4); pd += __shfl_xor(pd, 4);
        if ((tc & 7) == 0 && row < N) {
            as1[row * 4 + h] = ps;
            ad1[row * 4 + h] = pd;
        }
    }
}

// ---------------- gemm2 + fused alpha2 (h2 stays fp32) ----------------

__global__ __launch_bounds__(256) void gemm2_kernel(const float* __restrict__ x1,
                             const float* __restrict__ W2,
                             float* __restrict__ h2,
                             const float* __restrict__ a_s2, const float* __restrict__ a_d2,
                             float* __restrict__ as2, float* __restrict__ ad2, int N) {
    __shared__ float xs[64][128];
    __shared__ float ws[128][64];
    int tid = threadIdx.x;
    int r0 = blockIdx.x * 64;
    {
        const float4* W4 = (const float4*)W2;
        float4* ws4 = (float4*)ws;
        for (int i = tid; i < 128 * 16; i += 256) ws4[i] = W4[i];
    }
    {
        float4* xs4 = (float4*)xs;
        for (int i = tid; i < 64 * 32; i += 256) {
            int r = i >> 5, c = i & 31;
            int row = r0 + r;
            float4 v = make_float4(0.f, 0.f, 0.f, 0.f);
            if (row < N) v = ((const float4*)x1)[(size_t)row * 32 + c];
            xs4[i] = v;
        }
    }
    __syncthreads();
    int tr = tid >> 4;
    int tc = tid & 15;
    float4 acc[4];
    acc[0] = acc[1] = acc[2] = acc[3] = make_float4(0.f, 0.f, 0.f, 0.f);
    for (int k = 0; k < 128; k += 4) {
        float4 wv0 = *(const float4*)&ws[k][tc * 4];
        float4 wv1 = *(const float4*)&ws[k + 1][tc * 4];
        float4 wv2 = *(const float4*)&ws[k + 2][tc * 4];
        float4 wv3 = *(const float4*)&ws[k + 3][tc * 4];
#pragma unroll
        for (int i = 0; i < 4; i++) {
            float4 xv = *(const float4*)&xs[tr * 4 + i][k];
            acc[i].x = fmaf(xv.x, wv0.x, acc[i].x);
            acc[i].y = fmaf(xv.x, wv0.y, acc[i].y);
            acc[i].z = fmaf(xv.x, wv0.z, acc[i].z);
            acc[i].w = fmaf(xv.x, wv0.w, acc[i].w);
            acc[i].x = fmaf(xv.y, wv1.x, acc[i].x);
            acc[i].y = fmaf(xv.y, wv1.y, acc[i].y);
            acc[i].z = fmaf(xv.y, wv1.z, acc[i].z);
            acc[i].w = fmaf(xv.y, wv1.w, acc[i].w);
            acc[i].x = fmaf(xv.z, wv2.x, acc[i].x);
            acc[i].y = fmaf(xv.z, wv2.y, acc[i].y);
            acc[i].z = fmaf(xv.z, wv2.z, acc[i].z);
            acc[i].w = fmaf(xv.z, wv2.w, acc[i].w);
            acc[i].x = fmaf(xv.w, wv3.x, acc[i].x);
            acc[i].y = fmaf(xv.w, wv3.y, acc[i].y);
            acc[i].z = fmaf(xv.w, wv3.z, acc[i].z);
            acc[i].w = fmaf(xv.w, wv3.w, acc[i].w);
        }
    }
    // epilogue: h2 fp32 + fused alpha2 (single head = all 64 cols)
    float4 av = *(const float4*)&a_s2[tc * 4];
    float4 dv = *(const float4*)&a_d2[tc * 4];
#pragma unroll
    for (int i = 0; i < 4; i++) {
        int row = r0 + tr * 4 + i;
        if (row < N) *(float4*)&h2[(size_t)row * 64 + tc * 4] = acc[i];
        float ps = dot4(acc[i], av);
        float pd = dot4(acc[i], dv);
        ps += __shfl_xor(ps, 1); pd += __shfl_xor(pd, 1);
        ps += __shfl_xor(ps, 2); pd += __shfl_xor(pd, 2);
        ps += __shfl_xor(ps, 4); pd += __shfl_xor(pd, 4);
        ps += __shfl_xor(ps, 8); pd += __shfl_xor(pd, 8);
        if (tc == 0 && row < N) { as2[row] = ps; ad2[row] = pd; }
    }
}

// ---------------- aggregation: wave-per-node register softmax ----------------
// agg1 phase B gathers bf16 h1 (4 B/lane/edge -> half the fetch lines).

__global__ void __launch_bounds__(256)
agg1_kernel(const int* __restrict__ csr, const int* __restrict__ indptr,
            const int* __restrict__ counts, const float* __restrict__ as1,
            const float* __restrict__ ad1, const unsigned short* __restrict__ h1b,
            const float* __restrict__ b1, float* __restrict__ x1, int N) {
    int lane = threadIdx.x & 63;
    int n = blockIdx.x * 4 + (threadIdx.x >> 6);
    if (n >= N) return;
    int start = indptr[n];
    int cnt = counts[n];
    float4 ad4 = ((const float4*)ad1)[n];

    int src0 = 0;
    float4 e0 = make_float4(-1e30f, -1e30f, -1e30f, -1e30f);
    if (lane < cnt) {
        src0 = csr[start + lane];
        float4 a = ((const float4*)as1)[src0];
        e0.x = leaky(a.x + ad4.x);
        e0.y = leaky(a.y + ad4.y);
        e0.z = leaky(a.z + ad4.z);
        e0.w = leaky(a.w + ad4.w);
    }
    float4 m4 = e0;
#pragma unroll
    for (int off = 32; off >= 1; off >>= 1) {
        m4.x = fmaxf(m4.x, __shfl_xor(m4.x, off));
        m4.y = fmaxf(m4.y, __shfl_xor(m4.y, off));
        m4.z = fmaxf(m4.z, __shfl_xor(m4.z, off));
        m4.w = fmaxf(m4.w, __shfl_xor(m4.w, off));
    }
    if (cnt > 64) {
        for (int base = 64; base < cnt; base += 64) {
            float4 e = make_float4(-1e30f, -1e30f, -1e30f, -1e30f);
            if (base + lane < cnt) {
                int s = csr[start + base + lane];
                float4 a = ((const float4*)as1)[s];
                e.x = leaky(a.x + ad4.x); e.y = leaky(a.y + ad4.y);
                e.z = leaky(a.z + ad4.z); e.w = leaky(a.w + ad4.w);
            }
#pragma unroll
            for (int off = 32; off >= 1; off >>= 1) {
                e.x = fmaxf(e.x, __shfl_xor(e.x, off));
                e.y = fmaxf(e.y, __shfl_xor(e.y, off));
                e.z = fmaxf(e.z, __shfl_xor(e.z, off));
                e.w = fmaxf(e.w, __shfl_xor(e.w, off));
            }
            m4.x = fmaxf(m4.x, e.x); m4.y = fmaxf(m4.y, e.y);
            m4.z = fmaxf(m4.z, e.z); m4.w = fmaxf(m4.w, e.w);
        }
    }
    float4 p0;
    p0.x = __expf(e0.x - m4.x);
    p0.y = __expf(e0.y - m4.y);
    p0.z = __expf(e0.z - m4.z);
    p0.w = __expf(e0.w - m4.w);
    float4 l4 = p0;
#pragma unroll
    for (int off = 32; off >= 1; off >>= 1) {
        l4.x += __shfl_xor(l4.x, off);
        l4.y += __shfl_xor(l4.y, off);
        l4.z += __shfl_xor(l4.z, off);
        l4.w += __shfl_xor(l4.w, off);
    }
    if (cnt > 64) {
        for (int base = 64; base < cnt; base += 64) {
            float4 p = make_float4(0.f, 0.f, 0.f, 0.f);
            if (base + lane < cnt) {
                int s = csr[start + base + lane];
                float4 a = ((const float4*)as1)[s];
                p.x = __expf(leaky(a.x + ad4.x) - m4.x);
                p.y = __expf(leaky(a.y + ad4.y) - m4.y);
                p.z = __expf(leaky(a.z + ad4.z) - m4.z);
                p.w = __expf(leaky(a.w + ad4.w) - m4.w);
            }
#pragma unroll
            for (int off = 32; off >= 1; off >>= 1) {
                p.x += __shfl_xor(p.x, off);
                p.y += __shfl_xor(p.y, off);
                p.z += __shfl_xor(p.z, off);
                p.w += __shfl_xor(p.w, off);
            }
            l4.x += p.x; l4.y += p.y; l4.z += p.z; l4.w += p.w;
        }
    }
    float4 li = make_float4(1.f / l4.x, 1.f / l4.y, 1.f / l4.z, 1.f / l4.w);
    float4 w0 = make_float4(p0.x * li.x, p0.y * li.y, p0.z * li.z, p0.w * li.w);

    // phase B: lane owns channel pair c = lane*2 (head = lane>>4); bf16 payload
    int h = lane >> 4;
    const unsigned int* h1v = (const unsigned int*)h1b;   // 1 uint = 2 bf16
    float ax = 0.f, ay = 0.f;
    int nn = min(cnt, 64);
    int j = 0;
    for (; j + 4 <= nn; j += 4) {
        int s0 = __shfl(src0, j),     s1 = __shfl(src0, j + 1);
        int s2 = __shfl(src0, j + 2), s3 = __shfl(src0, j + 3);
        float wx0 = __shfl(w0.x, j), wy0 = __shfl(w0.y, j), wz0 = __shfl(w0.z, j), ww0 = __shfl(w0.w, j);
        float wx1 = __shfl(w0.x, j+1), wy1 = __shfl(w0.y, j+1), wz1 = __shfl(w0.z, j+1), ww1 = __shfl(w0.w, j+1);
        float wx2 = __shfl(w0.x, j+2), wy2 = __shfl(w0.y, j+2), wz2 = __shfl(w0.z, j+2), ww2 = __shfl(w0.w, j+2);
        float wx3 = __shfl(w0.x, j+3), wy3 = __shfl(w0.y, j+3), wz3 = __shfl(w0.z, j+3), ww3 = __shfl(w0.w, j+3);
        unsigned int u0 = h1v[(size_t)s0 * 64 + lane];
        unsigned int u1 = h1v[(size_t)s1 * 64 + lane];
        unsigned int u2 = h1v[(size_t)s2 * 64 + lane];
        unsigned int u3 = h1v[(size_t)s3 * 64 + lane];
        float w_0 = (h < 2) ? ((h == 0) ? wx0 : wy0) : ((h == 2) ? wz0 : ww0);
        float w_1 = (h < 2) ? ((h == 0) ? wx1 : wy1) : ((h == 2) ? wz1 : ww1);
        float w_2 = (h < 2) ? ((h == 0) ? wx2 : wy2) : ((h == 2) ? wz2 : ww2);
        float w_3 = (h < 2) ? ((h == 0) ? wx3 : wy3) : ((h == 2) ? wz3 : ww3);
        ax = fmaf(w_0, __uint_as_float(u0 << 16), ax);
        ay = fmaf(w_0, __uint_as_float(u0 & 0xffff0000u), ay);
        ax = fmaf(w_1, __uint_as_float(u1 << 16), ax);
        ay = fmaf(w_1, __uint_as_float(u1 & 0xffff0000u), ay);
        ax = fmaf(w_2, __uint_as_float(u2 << 16), ax);
        ay = fmaf(w_2, __uint_as_float(u2 & 0xffff0000u), ay);
        ax = fmaf(w_3, __uint_as_float(u3 << 16), ax);
        ay = fmaf(w_3, __uint_as_float(u3 & 0xffff0000u), ay);
    }
    for (; j < nn; j++) {
        int s = __shfl(src0, j);
        float wx = __shfl(w0.x, j), wy = __shfl(w0.y, j), wz = __shfl(w0.z, j), ww = __shfl(w0.w, j);
        float w = (h < 2) ? ((h == 0) ? wx : wy) : ((h == 2) ? wz : ww);
        unsigned int u = h1v[(size_t)s * 64 + lane];
        ax = fmaf(w, __uint_as_float(u << 16), ax);
        ay = fmaf(w, __uint_as_float(u & 0xffff0000u), ay);
    }
    if (cnt > 64) {
        for (int base = 64; base < cnt; base += 64) {
            int srcc = 0;
            float4 wc = make_float4(0.f, 0.f, 0.f, 0.f);
            if (base + lane < cnt) {
                srcc = csr[start + base + lane];
                float4 a = ((const float4*)as1)[srcc];
                wc.x = __expf(leaky(a.x + ad4.x) - m4.x) * li.x;
                wc.y = __expf(leaky(a.y + ad4.y) - m4.y) * li.y;
                wc.z = __expf(leaky(a.z + ad4.z) - m4.z) * li.z;
                wc.w = __expf(leaky(a.w + ad4.w) - m4.w) * li.w;
            }
            int mm = min(cnt - base, 64);
            for (int k = 0; k < mm; k++) {
                int s = __shfl(srcc, k);
                float wx = __shfl(wc.x, k), wy = __shfl(wc.y, k), wz = __shfl(wc.z, k), ww = __shfl(wc.w, k);
                float w = (h < 2) ? ((h == 0) ? wx : wy) : ((h == 2) ? wz : ww);
                unsigned int u = h1v[(size_t)s * 64 + lane];
                ax = fmaf(w, __uint_as_float(u << 16), ax);
                ay = fmaf(w, __uint_as_float(u & 0xffff0000u), ay);
            }
        }
    }
    float2 b = ((const float2*)b1)[lane];
    float ox = ax + b.x, oy = ay + b.y;
    ox = (ox > 0.f) ? ox : (__expf(ox) - 1.f);   // ELU
    oy = (oy > 0.f) ? oy : (__expf(oy) - 1.f);
    ((float2*)x1)[(size_t)n * 64 + lane] = make_float2(ox, oy);
}

__global__ void __launch_bounds__(256)
agg2_kernel(const int* __restrict__ csr, const int* __restrict__ indptr,
            const int* __restrict__ counts, const float* __restrict__ as2,
            const float* __restrict__ ad2, const float* __restrict__ h2,
            const float* __restrict__ b2, float* __restrict__ out, int N) {
    int lane = threadIdx.x & 63;
    int n = blockIdx.x * 4 + (threadIdx.x >> 6);
    if (n >= N) return;
    int start = indptr[n];
    int cnt = counts[n];
    float ad = ad2[n];

    int src0 = 0;
    float e0 = -1e30f;
    if (lane < cnt) {
        src0 = csr[start + lane];
        e0 = leaky(as2[src0] + ad);
    }
    float m = e0;
#pragma unroll
    for (int off = 32; off >= 1; off >>= 1) m = fmaxf(m, __shfl_xor(m, off));
    if (cnt > 64) {
        for (int base = 64; base < cnt; base += 64) {
            float e = -1e30f;
            if (base + lane < cnt) e = leaky(as2[csr[start + base + lane]] + ad);
#pragma unroll
            for (int off = 32; off >= 1; off >>= 1) e = fmaxf(e, __shfl_xor(e, off));
            m = fmaxf(m, e);
        }
    }
    float p0 = __expf(e0 - m);
    float l = p0;
#pragma unroll
    for (int off = 32; off >= 1; off >>= 1) l += __shfl_xor(l, off);
    if (cnt > 64) {
        for (int base = 64; base < cnt; base += 64) {
            float p = 0.f;
            if (base + lane < cnt) p = __expf(leaky(as2[csr[start + base + lane]] + ad) - m);
#pragma unroll
            for (int off = 32; off >= 1; off >>= 1) p += __shfl_xor(p, off);
            l += p;
        }
    }
    float li = 1.f / l;
    float w0 = p0 * li;

    float acc = 0.f;
    int nn = min(cnt, 64);
    int j = 0;
    for (; j + 4 <= nn; j += 4) {
        int s0 = __shfl(src0, j),     s1 = __shfl(src0, j + 1);
        int s2 = __shfl(src0, j + 2), s3 = __shfl(src0, j + 3);
        float w_0 = __shfl(w0, j),     w_1 = __shfl(w0, j + 1);
        float w_2 = __shfl(w0, j + 2), w_3 = __shfl(w0, j + 3);
        float v0 = h2[(size_t)s0 * 64 + lane];
        float v1 = h2[(size_t)s1 * 64 + lane];
        float v2 = h2[(size_t)s2 * 64 + lane];
        float v3 = h2[(size_t)s3 * 64 + lane];
        acc = fmaf(w_0, v0, acc);
        acc = fmaf(w_1, v1, acc);
        acc = fmaf(w_2, v2, acc);
        acc = fmaf(w_3, v3, acc);
    }
    for (; j < nn; j++) {
        acc = fmaf(__shfl(w0, j), h2[(size_t)__shfl(src0, j) * 64 + lane], acc);
    }
    if (cnt > 64) {
        for (int base = 64; base < cnt; base += 64) {
            int srcc = 0;
            float wc = 0.f;
            if (base + lane < cnt) {
                srcc = csr[start + base + lane];
                wc = __expf(leaky(as2[srcc] + ad) - m) * li;
            }
            int mm = min(cnt - base, 64);
            for (int k = 0; k < mm; k++) {
                acc = fmaf(__shfl(wc, k), h2[(size_t)__shfl(srcc, k) * 64 + lane], acc);
            }
        }
    }
    out[(size_t)n * 64 + lane] = acc + b2[lane];
}

// ---------------- launcher ----------------

extern "C" void kernel_launch(void* const* d_in, const int* in_sizes, int n_in,
                              void* d_out, int out_size, void* d_ws, size_t ws_size,
                              hipStream_t stream) {
    const int*   xidx = (const int*)d_in[0];
    const int*   ei   = (const int*)d_in[1];
    const float* emb  = (const float*)d_in[2];
    const float* W1   = (const float*)d_in[3];
    const float* a_s1 = (const float*)d_in[4];
    const float* a_d1 = (const float*)d_in[5];
    const float* b1   = (const float*)d_in[6];
    const float* W2   = (const float*)d_in[7];
    const float* a_s2 = (const float*)d_in[8];
    const float* a_d2 = (const float*)d_in[9];
    const float* b2   = (const float*)d_in[10];
    float* out = (float*)d_out;

    const int N  = in_sizes[0];
    const int E  = in_sizes[1] / 2;
    const int E2 = E + N;
    const int B  = (N + 255) / 256;

    // workspace layout
    int* ws_i   = (int*)d_ws;
    int* counts = ws_i;
    int* indptr = ws_i + N;
    int* cursor = ws_i + 2 * (size_t)N;
    int* bs     = ws_i + 3 * (size_t)N;
    int* csr    = ws_i + 3 * (size_t)N + 512;
    size_t fbase = ((size_t)(3 * (size_t)N + 512 + E2) + 3) & ~(size_t)3;
    float* ws_f = (float*)d_ws;
    unsigned short* h1b = (unsigned short*)(ws_f + fbase);   // N*128 bf16 = N*64 floats
    float* x1  = ws_f + fbase + (size_t)N * 64;              // N*128 floats
    float* as1 = x1 + (size_t)N * 128;                       // N*4
    float* ad1 = as1 + (size_t)N * 4;                        // N*4
    float* h2  = (float*)h1b;   // alias: h1b dead after agg1 (N*64 fp32 = same bytes)
    float* as2 = as1;           // alias: as1 dead after agg1
    float* ad2 = ad1;

    // CSR build
    zero_kernel<<<(N + 255) / 256, 256, 0, stream>>>(counts, N);
    hist_kernel<<<(E2 + 255) / 256, 256, 0, stream>>>(ei, E, E2, counts);
    scan1_kernel<<<B, 256, 0, stream>>>(counts, N, indptr, bs);
    scan2_kernel<<<1, 512, 0, stream>>>(bs, B);
    scan3_kernel<<<(N + 255) / 256, 256, 0, stream>>>(indptr, cursor, bs, N);
    scatter_kernel<<<(E2 + 255) / 256, 256, 0, stream>>>(ei, E, E2, cursor, csr);

    // Layer 1 (gemm1 fuses alpha1 + bf16 h1)
    {
        dim3 g((N + 63) / 64, 2);
        gemm1_kernel<<<g, 256, 0, stream>>>(emb, xidx, W1, h1b, a_s1, a_d1, as1, ad1, N);
    }
    agg1_kernel<<<(N + 3) / 4, 256, 0, stream>>>(csr, indptr, counts, as1, ad1, h1b, b1, x1, N);

    // Layer 2 (gemm2 fuses alpha2)
    gemm2_kernel<<<(N + 63) / 64, 256, 0, stream>>>(x1, W2, h2, a_s2, a_d2, as2, ad2, N);
    agg2_kernel<<<(N + 3) / 4, 256, 0, stream>>>(csr, indptr, counts, as2, ad2, h2, b2, out, N);
}

// Round 6
// 576.054 us; speedup vs baseline: 1.1300x; 1.0981x over previous
//
#include <hip/hip_runtime.h>
#include <math.h>

// GATNet: N=100000 nodes, D=128, HEADS=4, HID=32, OUT_C=64, E=1.6M (+N self-loops)
#define NEG_SLOPE 0.2f

__device__ __forceinline__ float leaky(float x) { return x > 0.f ? x : NEG_SLOPE * x; }
__device__ __forceinline__ float dot4(float4 a, float4 b) {
    return a.x * b.x + a.y * b.y + a.z * b.z + a.w * b.w;
}
// fp32 -> bf16 round-to-nearest-even
__device__ __forceinline__ unsigned short f2bf(float f) {
    unsigned int x = __float_as_uint(f);
    unsigned int r = (x + 0x7fffu + ((x >> 16) & 1u)) >> 16;
    return (unsigned short)r;
}
__device__ __forceinline__ float bflo(unsigned int u) { return __uint_as_float(u << 16); }
__device__ __forceinline__ float bfhi(unsigned int u) { return __uint_as_float(u & 0xffff0000u); }

// ---------------- CSR build ----------------

__global__ void zero_kernel(int* __restrict__ p, int n) {
    int i = blockIdx.x * blockDim.x + threadIdx.x;
    if (i < n) p[i] = 0;
}

__global__ void hist_kernel(const int* __restrict__ ei, int E, int E2, int* __restrict__ counts) {
    int e = blockIdx.x * blockDim.x + threadIdx.x;
    if (e >= E2) return;
    int dst = (e < E) ? ei[E + e] : (e - E);   // self-loop tail
    atomicAdd(&counts[dst], 1);
}

__global__ void scan1_kernel(const int* __restrict__ counts, int N,
                             int* __restrict__ indptr, int* __restrict__ bs) {
    __shared__ int s[256];
    int t = threadIdx.x;
    int i = blockIdx.x * 256 + t;
    int v = (i < N) ? counts[i] : 0;
    s[t] = v;
    __syncthreads();
    for (int off = 1; off < 256; off <<= 1) {
        int u = (t >= off) ? s[t - off] : 0;
        __syncthreads();
        s[t] += u;
        __syncthreads();
    }
    if (i < N) indptr[i] = s[t] - v;
    if (t == 255) bs[blockIdx.x] = s[255];
}

__global__ void scan2_kernel(int* __restrict__ bs, int B) {
    __shared__ int s[512];
    int t = threadIdx.x;
    s[t] = (t < B) ? bs[t] : 0;
    __syncthreads();
    for (int off = 1; off < 512; off <<= 1) {
        int u = (t >= off) ? s[t - off] : 0;
        __syncthreads();
        s[t] += u;
        __syncthreads();
    }
    if (t < B) bs[t] = (t == 0) ? 0 : s[t - 1];
}

__global__ void scan3_kernel(int* __restrict__ indptr, int* __restrict__ cursor,
                             const int* __restrict__ bs, int N) {
    int i = blockIdx.x * blockDim.x + threadIdx.x;
    if (i >= N) return;
    int v = indptr[i] + bs[i >> 8];
    indptr[i] = v;
    cursor[i] = v;
}

__global__ void scatter_kernel(const int* __restrict__ ei, int E, int E2,
                               int* __restrict__ cursor, int* __restrict__ csr_src) {
    int e = blockIdx.x * blockDim.x + threadIdx.x;
    if (e >= E2) return;
    int src, dst;
    if (e < E) { src = ei[e]; dst = ei[E + e]; }
    else       { src = e - E; dst = e - E; }
    int pos = atomicAdd(&cursor[dst], 1);
    csr_src[pos] = src;
}

// ---------------- gemm1 + fused alpha1, bf16 h1 output ----------------

__global__ __launch_bounds__(256) void gemm1_kernel(const float* __restrict__ emb,
                             const int* __restrict__ xidx,
                             const float* __restrict__ W1,
                             unsigned short* __restrict__ h1b,
                             const float* __restrict__ a_s1, const float* __restrict__ a_d1,
                             float* __restrict__ as1, float* __restrict__ ad1, int N) {
    __shared__ float xs[64][128];
    __shared__ float ws[128][64];
    int tid = threadIdx.x;
    int r0 = blockIdx.x * 64;
    int c0 = blockIdx.y * 64;
    {
        const float4* W4 = (const float4*)W1;
        float4* ws4 = (float4*)ws;
        int cbase = c0 >> 2;
        for (int i = tid; i < 128 * 16; i += 256) {
            int k = i >> 4, c = i & 15;
            ws4[i] = W4[k * 32 + cbase + c];
        }
    }
    {
        float4* xs4 = (float4*)xs;
        for (int i = tid; i < 64 * 32; i += 256) {
            int r = i >> 5, c = i & 31;
            int row = r0 + r;
            float4 v = make_float4(0.f, 0.f, 0.f, 0.f);
            if (row < N) {
                int s = xidx[row];
                v = ((const float4*)emb)[(size_t)s * 32 + c];
            }
            xs4[i] = v;
        }
    }
    __syncthreads();
    int tr = tid >> 4;
    int tc = tid & 15;
    float4 acc[4];
    acc[0] = acc[1] = acc[2] = acc[3] = make_float4(0.f, 0.f, 0.f, 0.f);
    for (int k = 0; k < 128; k += 4) {
        float4 wv0 = *(const float4*)&ws[k][tc * 4];
        float4 wv1 = *(const float4*)&ws[k + 1][tc * 4];
        float4 wv2 = *(const float4*)&ws[k + 2][tc * 4];
        float4 wv3 = *(const float4*)&ws[k + 3][tc * 4];
#pragma unroll
        for (int i = 0; i < 4; i++) {
            float4 xv = *(const float4*)&xs[tr * 4 + i][k];
            acc[i].x = fmaf(xv.x, wv0.x, acc[i].x);
            acc[i].y = fmaf(xv.x, wv0.y, acc[i].y);
            acc[i].z = fmaf(xv.x, wv0.z, acc[i].z);
            acc[i].w = fmaf(xv.x, wv0.w, acc[i].w);
            acc[i].x = fmaf(xv.y, wv1.x, acc[i].x);
            acc[i].y = fmaf(xv.y, wv1.y, acc[i].y);
            acc[i].z = fmaf(xv.y, wv1.z, acc[i].z);
            acc[i].w = fmaf(xv.y, wv1.w, acc[i].w);
            acc[i].x = fmaf(xv.z, wv2.x, acc[i].x);
            acc[i].y = fmaf(xv.z, wv2.y, acc[i].y);
            acc[i].z = fmaf(xv.z, wv2.z, acc[i].z);
            acc[i].w = fmaf(xv.z, wv2.w, acc[i].w);
            acc[i].x = fmaf(xv.w, wv3.x, acc[i].x);
            acc[i].y = fmaf(xv.w, wv3.y, acc[i].y);
            acc[i].z = fmaf(xv.w, wv3.z, acc[i].z);
            acc[i].w = fmaf(xv.w, wv3.w, acc[i].w);
        }
    }
    int colbase = c0 + tc * 4;
    int h = colbase >> 5;
    int off = colbase & 31;
    float4 av = *(const float4*)&a_s1[h * 32 + off];
    float4 dv = *(const float4*)&a_d1[h * 32 + off];
#pragma unroll
    for (int i = 0; i < 4; i++) {
        int row = r0 + tr * 4 + i;
        if (row < N) {
            ushort4 pk;
            pk.x = f2bf(acc[i].x); pk.y = f2bf(acc[i].y);
            pk.z = f2bf(acc[i].z); pk.w = f2bf(acc[i].w);
            *(ushort4*)&h1b[(size_t)row * 128 + colbase] = pk;
        }
        float ps = dot4(acc[i], av);
        float pd = dot4(acc[i], dv);
        ps += __shfl_xor(ps, 1); pd += __shfl_xor(pd, 1);
        ps += __shfl_xor(ps, 2); pd += __shfl_xor(pd, 2);
        ps += __shfl_xor(ps, 4); pd += __shfl_xor(pd, 4);
        if ((tc & 7) == 0 && row < N) {
            as1[row * 4 + h] = ps;
            ad1[row * 4 + h] = pd;
        }
    }
}

// ---------------- gemm2 + fused alpha2 (h2 stays fp32) ----------------

__global__ __launch_bounds__(256) void gemm2_kernel(const float* __restrict__ x1,
                             const float* __restrict__ W2,
                             float* __restrict__ h2,
                             const float* __restrict__ a_s2, const float* __restrict__ a_d2,
                             float* __restrict__ as2, float* __restrict__ ad2, int N) {
    __shared__ float xs[64][128];
    __shared__ float ws[128][64];
    int tid = threadIdx.x;
    int r0 = blockIdx.x * 64;
    {
        const float4* W4 = (const float4*)W2;
        float4* ws4 = (float4*)ws;
        for (int i = tid; i < 128 * 16; i += 256) ws4[i] = W4[i];
    }
    {
        float4* xs4 = (float4*)xs;
        for (int i = tid; i < 64 * 32; i += 256) {
            int r = i >> 5, c = i & 31;
            int row = r0 + r;
            float4 v = make_float4(0.f, 0.f, 0.f, 0.f);
            if (row < N) v = ((const float4*)x1)[(size_t)row * 32 + c];
            xs4[i] = v;
        }
    }
    __syncthreads();
    int tr = tid >> 4;
    int tc = tid & 15;
    float4 acc[4];
    acc[0] = acc[1] = acc[2] = acc[3] = make_float4(0.f, 0.f, 0.f, 0.f);
    for (int k = 0; k < 128; k += 4) {
        float4 wv0 = *(const float4*)&ws[k][tc * 4];
        float4 wv1 = *(const float4*)&ws[k + 1][tc * 4];
        float4 wv2 = *(const float4*)&ws[k + 2][tc * 4];
        float4 wv3 = *(const float4*)&ws[k + 3][tc * 4];
#pragma unroll
        for (int i = 0; i < 4; i++) {
            float4 xv = *(const float4*)&xs[tr * 4 + i][k];
            acc[i].x = fmaf(xv.x, wv0.x, acc[i].x);
            acc[i].y = fmaf(xv.x, wv0.y, acc[i].y);
            acc[i].z = fmaf(xv.x, wv0.z, acc[i].z);
            acc[i].w = fmaf(xv.x, wv0.w, acc[i].w);
            acc[i].x = fmaf(xv.y, wv1.x, acc[i].x);
            acc[i].y = fmaf(xv.y, wv1.y, acc[i].y);
            acc[i].z = fmaf(xv.y, wv1.z, acc[i].z);
            acc[i].w = fmaf(xv.y, wv1.w, acc[i].w);
            acc[i].x = fmaf(xv.z, wv2.x, acc[i].x);
            acc[i].y = fmaf(xv.z, wv2.y, acc[i].y);
            acc[i].z = fmaf(xv.z, wv2.z, acc[i].z);
            acc[i].w = fmaf(xv.z, wv2.w, acc[i].w);
            acc[i].x = fmaf(xv.w, wv3.x, acc[i].x);
            acc[i].y = fmaf(xv.w, wv3.y, acc[i].y);
            acc[i].z = fmaf(xv.w, wv3.z, acc[i].z);
            acc[i].w = fmaf(xv.w, wv3.w, acc[i].w);
        }
    }
    float4 av = *(const float4*)&a_s2[tc * 4];
    float4 dv = *(const float4*)&a_d2[tc * 4];
#pragma unroll
    for (int i = 0; i < 4; i++) {
        int row = r0 + tr * 4 + i;
        if (row < N) *(float4*)&h2[(size_t)row * 64 + tc * 4] = acc[i];
        float ps = dot4(acc[i], av);
        float pd = dot4(acc[i], dv);
        ps += __shfl_xor(ps, 1); pd += __shfl_xor(pd, 1);
        ps += __shfl_xor(ps, 2); pd += __shfl_xor(pd, 2);
        ps += __shfl_xor(ps, 4); pd += __shfl_xor(pd, 4);
        ps += __shfl_xor(ps, 8); pd += __shfl_xor(pd, 8);
        if (tc == 0 && row < N) { as2[row] = ps; ad2[row] = pd; }
    }
}

// ---------------- aggregation: 4 edges per gather instruction ----------------
// Wave per node. Phase B: 16 lanes per edge (uint4 = 8 bf16 channels per lane),
// 4 edges per wave-load, 2 loads in flight per iter (8 edges). Partial sums
// merged with 2 shfl_xor stages; lanes 0-15 write the row.

__device__ __forceinline__ void accum_group1(int srcReg, float4 wReg, int mcount,
                                             const uint4* __restrict__ h1v4,
                                             int sub, int cg, int hh, float* acc) {
    int b = 0;
    for (; b + 8 <= mcount; b += 8) {
        int i0 = b + sub, i1 = b + 4 + sub;
        int s0 = __shfl(srcReg, i0);
        int s1 = __shfl(srcReg, i1);
        float wx0 = __shfl(wReg.x, i0), wy0 = __shfl(wReg.y, i0);
        float wz0 = __shfl(wReg.z, i0), ww0 = __shfl(wReg.w, i0);
        float wx1 = __shfl(wReg.x, i1), wy1 = __shfl(wReg.y, i1);
        float wz1 = __shfl(wReg.z, i1), ww1 = __shfl(wReg.w, i1);
        uint4 u0 = h1v4[(size_t)s0 * 16 + cg];
        uint4 u1 = h1v4[(size_t)s1 * 16 + cg];
        float w_0 = (hh < 2) ? ((hh == 0) ? wx0 : wy0) : ((hh == 2) ? wz0 : ww0);
        float w_1 = (hh < 2) ? ((hh == 0) ? wx1 : wy1) : ((hh == 2) ? wz1 : ww1);
        acc[0] = fmaf(w_0, bflo(u0.x), acc[0]); acc[1] = fmaf(w_0, bfhi(u0.x), acc[1]);
        acc[2] = fmaf(w_0, bflo(u0.y), acc[2]); acc[3] = fmaf(w_0, bfhi(u0.y), acc[3]);
        acc[4] = fmaf(w_0, bflo(u0.z), acc[4]); acc[5] = fmaf(w_0, bfhi(u0.z), acc[5]);
        acc[6] = fmaf(w_0, bflo(u0.w), acc[6]); acc[7] = fmaf(w_0, bfhi(u0.w), acc[7]);
        acc[0] = fmaf(w_1, bflo(u1.x), acc[0]); acc[1] = fmaf(w_1, bfhi(u1.x), acc[1]);
        acc[2] = fmaf(w_1, bflo(u1.y), acc[2]); acc[3] = fmaf(w_1, bfhi(u1.y), acc[3]);
        acc[4] = fmaf(w_1, bflo(u1.z), acc[4]); acc[5] = fmaf(w_1, bfhi(u1.z), acc[5]);
        acc[6] = fmaf(w_1, bflo(u1.w), acc[6]); acc[7] = fmaf(w_1, bfhi(u1.w), acc[7]);
    }
    for (; b + 4 <= mcount; b += 4) {
        int i0 = b + sub;
        int s0 = __shfl(srcReg, i0);
        float wx = __shfl(wReg.x, i0), wy = __shfl(wReg.y, i0);
        float wz = __shfl(wReg.z, i0), ww = __shfl(wReg.w, i0);
        uint4 u0 = h1v4[(size_t)s0 * 16 + cg];
        float w = (hh < 2) ? ((hh == 0) ? wx : wy) : ((hh == 2) ? wz : ww);
        acc[0] = fmaf(w, bflo(u0.x), acc[0]); acc[1] = fmaf(w, bfhi(u0.x), acc[1]);
        acc[2] = fmaf(w, bflo(u0.y), acc[2]); acc[3] = fmaf(w, bfhi(u0.y), acc[3]);
        acc[4] = fmaf(w, bflo(u0.z), acc[4]); acc[5] = fmaf(w, bfhi(u0.z), acc[5]);
        acc[6] = fmaf(w, bflo(u0.w), acc[6]); acc[7] = fmaf(w, bfhi(u0.w), acc[7]);
    }
    if (b < mcount) {
        int rem = mcount - b;
        int i0 = b + sub;
        int s0 = __shfl(srcReg, i0);
        float wx = __shfl(wReg.x, i0), wy = __shfl(wReg.y, i0);
        float wz = __shfl(wReg.z, i0), ww = __shfl(wReg.w, i0);
        if (sub < rem) {
            uint4 u0 = h1v4[(size_t)s0 * 16 + cg];
            float w = (hh < 2) ? ((hh == 0) ? wx : wy) : ((hh == 2) ? wz : ww);
            acc[0] = fmaf(w, bflo(u0.x), acc[0]); acc[1] = fmaf(w, bfhi(u0.x), acc[1]);
            acc[2] = fmaf(w, bflo(u0.y), acc[2]); acc[3] = fmaf(w, bfhi(u0.y), acc[3]);
            acc[4] = fmaf(w, bflo(u0.z), acc[4]); acc[5] = fmaf(w, bfhi(u0.z), acc[5]);
            acc[6] = fmaf(w, bflo(u0.w), acc[6]); acc[7] = fmaf(w, bfhi(u0.w), acc[7]);
        }
    }
}

__global__ void __launch_bounds__(256)
agg1_kernel(const int* __restrict__ csr, const int* __restrict__ indptr,
            const int* __restrict__ counts, const float* __restrict__ as1,
            const float* __restrict__ ad1, const unsigned short* __restrict__ h1b,
            const float* __restrict__ b1, float* __restrict__ x1, int N) {
    int lane = threadIdx.x & 63;
    int n = blockIdx.x * 4 + (threadIdx.x >> 6);
    if (n >= N) return;
    int start = indptr[n];
    int cnt = counts[n];
    float4 ad4 = ((const float4*)ad1)[n];

    // Phase A: lane i <-> edge i (first 64 edges)
    int src0 = 0;
    float4 e0 = make_float4(-1e30f, -1e30f, -1e30f, -1e30f);
    if (lane < cnt) {
        src0 = csr[start + lane];
        float4 a = ((const float4*)as1)[src0];
        e0.x = leaky(a.x + ad4.x);
        e0.y = leaky(a.y + ad4.y);
        e0.z = leaky(a.z + ad4.z);
        e0.w = leaky(a.w + ad4.w);
    }
    float4 m4 = e0;
#pragma unroll
    for (int off = 32; off >= 1; off >>= 1) {
        m4.x = fmaxf(m4.x, __shfl_xor(m4.x, off));
        m4.y = fmaxf(m4.y, __shfl_xor(m4.y, off));
        m4.z = fmaxf(m4.z, __shfl_xor(m4.z, off));
        m4.w = fmaxf(m4.w, __shfl_xor(m4.w, off));
    }
    if (cnt > 64) {
        for (int base = 64; base < cnt; base += 64) {
            float4 e = make_float4(-1e30f, -1e30f, -1e30f, -1e30f);
            if (base + lane < cnt) {
                int s = csr[start + base + lane];
                float4 a = ((const float4*)as1)[s];
                e.x = leaky(a.x + ad4.x); e.y = leaky(a.y + ad4.y);
                e.z = leaky(a.z + ad4.z); e.w = leaky(a.w + ad4.w);
            }
#pragma unroll
            for (int off = 32; off >= 1; off >>= 1) {
                e.x = fmaxf(e.x, __shfl_xor(e.x, off));
                e.y = fmaxf(e.y, __shfl_xor(e.y, off));
                e.z = fmaxf(e.z, __shfl_xor(e.z, off));
                e.w = fmaxf(e.w, __shfl_xor(e.w, off));
            }
            m4.x = fmaxf(m4.x, e.x); m4.y = fmaxf(m4.y, e.y);
            m4.z = fmaxf(m4.z, e.z); m4.w = fmaxf(m4.w, e.w);
        }
    }
    float4 p0;
    p0.x = __expf(e0.x - m4.x);
    p0.y = __expf(e0.y - m4.y);
    p0.z = __expf(e0.z - m4.z);
    p0.w = __expf(e0.w - m4.w);
    float4 l4 = p0;
#pragma unroll
    for (int off = 32; off >= 1; off >>= 1) {
        l4.x += __shfl_xor(l4.x, off);
        l4.y += __shfl_xor(l4.y, off);
        l4.z += __shfl_xor(l4.z, off);
        l4.w += __shfl_xor(l4.w, off);
    }
    if (cnt > 64) {
        for (int base = 64; base < cnt; base += 64) {
            float4 p = make_float4(0.f, 0.f, 0.f, 0.f);
            if (base + lane < cnt) {
                int s = csr[start + base + lane];
                float4 a = ((const float4*)as1)[s];
                p.x = __expf(leaky(a.x + ad4.x) - m4.x);
                p.y = __expf(leaky(a.y + ad4.y) - m4.y);
                p.z = __expf(leaky(a.z + ad4.z) - m4.z);
                p.w = __expf(leaky(a.w + ad4.w) - m4.w);
            }
#pragma unroll
            for (int off = 32; off >= 1; off >>= 1) {
                p.x += __shfl_xor(p.x, off);
                p.y += __shfl_xor(p.y, off);
                p.z += __shfl_xor(p.z, off);
                p.w += __shfl_xor(p.w, off);
            }
            l4.x += p.x; l4.y += p.y; l4.z += p.z; l4.w += p.w;
        }
    }
    float4 li = make_float4(1.f / l4.x, 1.f / l4.y, 1.f / l4.z, 1.f / l4.w);
    float4 w0 = make_float4(p0.x * li.x, p0.y * li.y, p0.z * li.z, p0.w * li.w);

    // Phase B: 4 edges per load. sub = edge-within-group, cg = channel group.
    int sub = lane >> 4;
    int cg = lane & 15;
    int hh = cg >> 2;           // head of channels [cg*8, cg*8+8)
    const uint4* h1v4 = (const uint4*)h1b;
    float acc[8] = {0.f, 0.f, 0.f, 0.f, 0.f, 0.f, 0.f, 0.f};
    accum_group1(src0, w0, min(cnt, 64), h1v4, sub, cg, hh, acc);
    if (cnt > 64) {
        for (int base = 64; base < cnt; base += 64) {
            int srcc = 0;
            float4 wc = make_float4(0.f, 0.f, 0.f, 0.f);
            if (base + lane < cnt) {
                srcc = csr[start + base + lane];
                float4 a = ((const float4*)as1)[srcc];
                wc.x = __expf(leaky(a.x + ad4.x) - m4.x) * li.x;
                wc.y = __expf(leaky(a.y + ad4.y) - m4.y) * li.y;
                wc.z = __expf(leaky(a.z + ad4.z) - m4.z) * li.z;
                wc.w = __expf(leaky(a.w + ad4.w) - m4.w) * li.w;
            }
            accum_group1(srcc, wc, min(cnt - base, 64), h1v4, sub, cg, hh, acc);
        }
    }
    // merge the 4 sub-group partials
#pragma unroll
    for (int i = 0; i < 8; i++) {
        acc[i] += __shfl_xor(acc[i], 16);
        acc[i] += __shfl_xor(acc[i], 32);
    }
    if (lane < 16) {
        float4 o0, o1;
        const float4* b4 = (const float4*)b1;
        float4 ba = b4[cg * 2], bb = b4[cg * 2 + 1];
        o0.x = acc[0] + ba.x; o0.y = acc[1] + ba.y; o0.z = acc[2] + ba.z; o0.w = acc[3] + ba.w;
        o1.x = acc[4] + bb.x; o1.y = acc[5] + bb.y; o1.z = acc[6] + bb.z; o1.w = acc[7] + bb.w;
        o0.x = (o0.x > 0.f) ? o0.x : (__expf(o0.x) - 1.f);
        o0.y = (o0.y > 0.f) ? o0.y : (__expf(o0.y) - 1.f);
        o0.z = (o0.z > 0.f) ? o0.z : (__expf(o0.z) - 1.f);
        o0.w = (o0.w > 0.f) ? o0.w : (__expf(o0.w) - 1.f);
        o1.x = (o1.x > 0.f) ? o1.x : (__expf(o1.x) - 1.f);
        o1.y = (o1.y > 0.f) ? o1.y : (__expf(o1.y) - 1.f);
        o1.z = (o1.z > 0.f) ? o1.z : (__expf(o1.z) - 1.f);
        o1.w = (o1.w > 0.f) ? o1.w : (__expf(o1.w) - 1.f);
        float4* xrow = (float4*)&x1[(size_t)n * 128 + cg * 8];
        xrow[0] = o0;
        xrow[1] = o1;
    }
}

__device__ __forceinline__ void accum_group2(int srcReg, float wReg, int mcount,
                                             const float4* __restrict__ h2v4,
                                             int sub, int cg, float4* acc) {
    int b = 0;
    for (; b + 8 <= mcount; b += 8) {
        int i0 = b + sub, i1 = b + 4 + sub;
        int s0 = __shfl(srcReg, i0);
        int s1 = __shfl(srcReg, i1);
        float w_0 = __shfl(wReg, i0);
        float w_1 = __shfl(wReg, i1);
        float4 v0 = h2v4[(size_t)s0 * 16 + cg];
        float4 v1 = h2v4[(size_t)s1 * 16 + cg];
        acc->x = fmaf(w_0, v0.x, acc->x); acc->y = fmaf(w_0, v0.y, acc->y);
        acc->z = fmaf(w_0, v0.z, acc->z); acc->w = fmaf(w_0, v0.w, acc->w);
        acc->x = fmaf(w_1, v1.x, acc->x); acc->y = fmaf(w_1, v1.y, acc->y);
        acc->z = fmaf(w_1, v1.z, acc->z); acc->w = fmaf(w_1, v1.w, acc->w);
    }
    for (; b + 4 <= mcount; b += 4) {
        int i0 = b + sub;
        int s0 = __shfl(srcReg, i0);
        float w_0 = __shfl(wReg, i0);
        float4 v0 = h2v4[(size_t)s0 * 16 + cg];
        acc->x = fmaf(w_0, v0.x, acc->x); acc->y = fmaf(w_0, v0.y, acc->y);
        acc->z = fmaf(w_0, v0.z, acc->z); acc->w = fmaf(w_0, v0.w, acc->w);
    }
    if (b < mcount) {
        int rem = mcount - b;
        int i0 = b + sub;
        int s0 = __shfl(srcReg, i0);
        float w_0 = __shfl(wReg, i0);
        if (sub < rem) {
            float4 v0 = h2v4[(size_t)s0 * 16 + cg];
            acc->x = fmaf(w_0, v0.x, acc->x); acc->y = fmaf(w_0, v0.y, acc->y);
            acc->z = fmaf(w_0, v0.z, acc->z); acc->w = fmaf(w_0, v0.w, acc->w);
        }
    }
}

__global__ void __launch_bounds__(256)
agg2_kernel(const int* __restrict__ csr, const int* __restrict__ indptr,
            const int* __restrict__ counts, const float* __restrict__ as2,
            const float* __restrict__ ad2, const float* __restrict__ h2,
            const float* __restrict__ b2, float* __restrict__ out, int N) {
    int lane = threadIdx.x & 63;
    int n = blockIdx.x * 4 + (threadIdx.x >> 6);
    if (n >= N) return;
    int start = indptr[n];
    int cnt = counts[n];
    float ad = ad2[n];

    int src0 = 0;
    float e0 = -1e30f;
    if (lane < cnt) {
        src0 = csr[start + lane];
        e0 = leaky(as2[src0] + ad);
    }
    float m = e0;
#pragma unroll
    for (int off = 32; off >= 1; off >>= 1) m = fmaxf(m, __shfl_xor(m, off));
    if (cnt > 64) {
        for (int base = 64; base < cnt; base += 64) {
            float e = -1e30f;
            if (base + lane < cnt) e = leaky(as2[csr[start + base + lane]] + ad);
#pragma unroll
            for (int off = 32; off >= 1; off >>= 1) e = fmaxf(e, __shfl_xor(e, off));
            m = fmaxf(m, e);
        }
    }
    float p0 = __expf(e0 - m);
    float l = p0;
#pragma unroll
    for (int off = 32; off >= 1; off >>= 1) l += __shfl_xor(l, off);
    if (cnt > 64) {
        for (int base = 64; base < cnt; base += 64) {
            float p = 0.f;
            if (base + lane < cnt) p = __expf(leaky(as2[csr[start + base + lane]] + ad) - m);
#pragma unroll
            for (int off = 32; off >= 1; off >>= 1) p += __shfl_xor(p, off);
            l += p;
        }
    }
    float li = 1.f / l;
    float w0 = p0 * li;

    int sub = lane >> 4;
    int cg = lane & 15;
    const float4* h2v4 = (const float4*)h2;
    float4 acc = make_float4(0.f, 0.f, 0.f, 0.f);
    accum_group2(src0, w0, min(cnt, 64), h2v4, sub, cg, &acc);
    if (cnt > 64) {
        for (int base = 64; base < cnt; base += 64) {
            int srcc = 0;
            float wc = 0.f;
            if (base + lane < cnt) {
                srcc = csr[start + base + lane];
                wc = __expf(leaky(as2[srcc] + ad) - m) * li;
            }
            accum_group2(srcc, wc, min(cnt - base, 64), h2v4, sub, cg, &acc);
        }
    }
    acc.x += __shfl_xor(acc.x, 16); acc.x += __shfl_xor(acc.x, 32);
    acc.y += __shfl_xor(acc.y, 16); acc.y += __shfl_xor(acc.y, 32);
    acc.z += __shfl_xor(acc.z, 16); acc.z += __shfl_xor(acc.z, 32);
    acc.w += __shfl_xor(acc.w, 16); acc.w += __shfl_xor(acc.w, 32);
    if (lane < 16) {
        float4 b = ((const float4*)b2)[cg];
        float4 o;
        o.x = acc.x + b.x; o.y = acc.y + b.y; o.z = acc.z + b.z; o.w = acc.w + b.w;
        ((float4*)out)[(size_t)n * 16 + cg] = o;
    }
}

// ---------------- launcher ----------------

extern "C" void kernel_launch(void* const* d_in, const int* in_sizes, int n_in,
                              void* d_out, int out_size, void* d_ws, size_t ws_size,
                              hipStream_t stream) {
    const int*   xidx = (const int*)d_in[0];
    const int*   ei   = (const int*)d_in[1];
    const float* emb  = (const float*)d_in[2];
    const float* W1   = (const float*)d_in[3];
    const float* a_s1 = (const float*)d_in[4];
    const float* a_d1 = (const float*)d_in[5];
    const float* b1   = (const float*)d_in[6];
    const float* W2   = (const float*)d_in[7];
    const float* a_s2 = (const float*)d_in[8];
    const float* a_d2 = (const float*)d_in[9];
    const float* b2   = (const float*)d_in[10];
    float* out = (float*)d_out;

    const int N  = in_sizes[0];
    const int E  = in_sizes[1] / 2;
    const int E2 = E + N;
    const int B  = (N + 255) / 256;

    // workspace layout
    int* ws_i   = (int*)d_ws;
    int* counts = ws_i;
    int* indptr = ws_i + N;
    int* cursor = ws_i + 2 * (size_t)N;
    int* bs     = ws_i + 3 * (size_t)N;
    int* csr    = ws_i + 3 * (size_t)N + 512;
    size_t fbase = ((size_t)(3 * (size_t)N + 512 + E2) + 3) & ~(size_t)3;
    float* ws_f = (float*)d_ws;
    unsigned short* h1b = (unsigned short*)(ws_f + fbase);   // N*128 bf16 = N*64 floats
    float* x1  = ws_f + fbase + (size_t)N * 64;              // N*128 floats
    float* as1 = x1 + (size_t)N * 128;                       // N*4
    float* ad1 = as1 + (size_t)N * 4;                        // N*4
    float* h2  = (float*)h1b;   // alias: h1b dead after agg1 (same byte count)
    float* as2 = as1;           // alias: as1 dead after agg1
    float* ad2 = ad1;

    // CSR build
    zero_kernel<<<(N + 255) / 256, 256, 0, stream>>>(counts, N);
    hist_kernel<<<(E2 + 255) / 256, 256, 0, stream>>>(ei, E, E2, counts);
    scan1_kernel<<<B, 256, 0, stream>>>(counts, N, indptr, bs);
    scan2_kernel<<<1, 512, 0, stream>>>(bs, B);
    scan3_kernel<<<(N + 255) / 256, 256, 0, stream>>>(indptr, cursor, bs, N);
    scatter_kernel<<<(E2 + 255) / 256, 256, 0, stream>>>(ei, E, E2, cursor, csr);

    // Layer 1 (gemm1 fuses alpha1 + bf16 h1)
    {
        dim3 g((N + 63) / 64, 2);
        gemm1_kernel<<<g, 256, 0, stream>>>(emb, xidx, W1, h1b, a_s1, a_d1, as1, ad1, N);
    }
    agg1_kernel<<<(N + 3) / 4, 256, 0, stream>>>(csr, indptr, counts, as1, ad1, h1b, b1, x1, N);

    // Layer 2 (gemm2 fuses alpha2)
    gemm2_kernel<<<(N + 63) / 64, 256, 0, stream>>>(x1, W2, h2, a_s2, a_d2, as2, ad2, N);
    agg2_kernel<<<(N + 3) / 4, 256, 0, stream>>>(csr, indptr, counts, as2, ad2, h2, b2, out, N);
}

// Round 7
// 475.350 us; speedup vs baseline: 1.3694x; 1.2119x over previous
//
#include <hip/hip_runtime.h>
#include <math.h>

// GATNet: N=100000 nodes, D=128, HEADS=4, HID=32, OUT_C=64, E=1.6M (+N self-loops)
#define NEG_SLOPE 0.2f
#define BK_SHIFT 8          // bucket = dst >> 8 (256 dsts per bucket)

__device__ __forceinline__ float leaky(float x) { return x > 0.f ? x : NEG_SLOPE * x; }
__device__ __forceinline__ float dot4(float4 a, float4 b) {
    return a.x * b.x + a.y * b.y + a.z * b.z + a.w * b.w;
}
// fp32 -> bf16 round-to-nearest-even
__device__ __forceinline__ unsigned short f2bf(float f) {
    unsigned int x = __float_as_uint(f);
    unsigned int r = (x + 0x7fffu + ((x >> 16) & 1u)) >> 16;
    return (unsigned short)r;
}
__device__ __forceinline__ float bflo(unsigned int u) { return __uint_as_float(u << 16); }
__device__ __forceinline__ float bfhi(unsigned int u) { return __uint_as_float(u & 0xffff0000u); }

// ---------------- CSR build: dst-radix partition ----------------

__global__ void zero_kernel(int* __restrict__ p, int n) {
    int i = blockIdx.x * blockDim.x + threadIdx.x;
    if (i < n) p[i] = 0;
}

// pass 0: bucket histogram via LDS (one global atomic per nonzero block-bin)
__global__ void __launch_bounds__(256) bcount_kernel(const int* __restrict__ ei, int E, int E2,
                                                     int K, int* __restrict__ bcounts) {
    __shared__ int h[512];
    int t = threadIdx.x;
    h[t] = 0; h[t + 256] = 0;
    __syncthreads();
    int base = blockIdx.x * 4096;
#pragma unroll 4
    for (int i = 0; i < 16; i++) {
        int e = base + i * 256 + t;
        if (e < E2) {
            int dst = (e < E) ? ei[E + e] : (e - E);
            atomicAdd(&h[dst >> BK_SHIFT], 1);
        }
    }
    __syncthreads();
    for (int b = t; b < K; b += 256) {
        int c = h[b];
        if (c) atomicAdd(&bcounts[b], c);
    }
}

// pass 1: exclusive scan of bucket counts (single block, K <= 512)
__global__ void __launch_bounds__(512) bscan_kernel(const int* __restrict__ bcounts, int K,
                                                    int* __restrict__ bbase, int* __restrict__ bcursor) {
    __shared__ int s[512];
    int t = threadIdx.x;
    int v = (t < K) ? bcounts[t] : 0;
    s[t] = v;
    __syncthreads();
    for (int off = 1; off < 512; off <<= 1) {
        int u = (t >= off) ? s[t - off] : 0;
        __syncthreads();
        s[t] += u;
        __syncthreads();
    }
    if (t < K) {
        int ex = s[t] - v;
        bbase[t] = ex;
        bcursor[t] = ex;
    }
    if (t == 511) bbase[K] = s[511];
}

// pass 2: LDS-reorder chunks of edges by bucket; write (src,dst) in coalesced runs
__global__ void __launch_bounds__(256) bscatter_kernel(const int* __restrict__ ei, int E, int E2,
                                                       int K, int* __restrict__ bcursor,
                                                       uint2* __restrict__ bedges) {
    __shared__ int hist[512], pre[512], lcur[512], gbase[512], psum[256];
    __shared__ uint2 stage[4096];
    int t = threadIdx.x;
    hist[t] = 0; hist[t + 256] = 0;
    __syncthreads();
    int base = blockIdx.x * 4096;
    int cnt = min(4096, E2 - base);
    int s_[16], d_[16];
#pragma unroll
    for (int i = 0; i < 16; i++) {
        int e = base + i * 256 + t;
        if (e < E2) {
            int ss, dd;
            if (e < E) { ss = ei[e]; dd = ei[E + e]; }
            else       { ss = e - E; dd = ss; }
            s_[i] = ss; d_[i] = dd;
            atomicAdd(&hist[dd >> BK_SHIFT], 1);
        }
    }
    __syncthreads();
    // exclusive scan of hist[512] with 256 threads (pair trick)
    int a0 = hist[2 * t], a1 = hist[2 * t + 1];
    psum[t] = a0 + a1;
    __syncthreads();
    for (int off = 1; off < 256; off <<= 1) {
        int u = (t >= off) ? psum[t - off] : 0;
        __syncthreads();
        psum[t] += u;
        __syncthreads();
    }
    int pex = psum[t] - (a0 + a1);
    pre[2 * t] = pex;
    pre[2 * t + 1] = pex + a0;
    __syncthreads();
    // reserve global space per bin; init local cursors
    for (int b = t; b < K; b += 256) {
        int c = hist[b];
        if (c) gbase[b] = atomicAdd(&bcursor[b], c);
    }
    lcur[t] = pre[t]; lcur[t + 256] = pre[t + 256];
    __syncthreads();
    // stage into bin-sorted LDS order
#pragma unroll
    for (int i = 0; i < 16; i++) {
        int e = base + i * 256 + t;
        if (e < E2) {
            int bin = d_[i] >> BK_SHIFT;
            int p = atomicAdd(&lcur[bin], 1);
            stage[p] = make_uint2((unsigned)s_[i], (unsigned)d_[i]);
        }
    }
    __syncthreads();
    // copy out: consecutive i -> mostly consecutive global addresses
    for (int i = t; i < cnt; i += 256) {
        uint2 ed = stage[i];
        int bin = (int)(ed.y >> BK_SHIFT);
        bedges[gbase[bin] + (i - pre[bin])] = ed;
    }
}

// pass 3: one block per bucket builds counts/indptr/csr for its 256-dst slice
__global__ void __launch_bounds__(256) bcsr_kernel(const uint2* __restrict__ bedges,
                                                   const int* __restrict__ bbase, int N,
                                                   int* __restrict__ counts, int* __restrict__ indptr,
                                                   int* __restrict__ csr) {
    __shared__ int hist[256], scn[256], cur[256];
    int b = blockIdx.x;
    int t = threadIdx.x;
    int base = bbase[b];
    int cnt = bbase[b + 1] - base;
    hist[t] = 0;
    __syncthreads();
    for (int i = t; i < cnt; i += 256) {
        atomicAdd(&hist[bedges[base + i].y & 255], 1);
    }
    __syncthreads();
    int v = hist[t];
    scn[t] = v;
    __syncthreads();
    for (int off = 1; off < 256; off <<= 1) {
        int u = (t >= off) ? scn[t - off] : 0;
        __syncthreads();
        scn[t] += u;
        __syncthreads();
    }
    int ex = scn[t] - v;
    int d = (b << BK_SHIFT) + t;
    if (d < N) { counts[d] = v; indptr[d] = base + ex; }
    cur[t] = ex;
    __syncthreads();
    for (int i = t; i < cnt; i += 256) {
        uint2 ed = bedges[base + i];
        int p = atomicAdd(&cur[ed.y & 255], 1);
        csr[base + p] = (int)ed.x;
    }
}

// ---------------- gemm1 + fused alpha1, bf16 h1 output ----------------

__global__ __launch_bounds__(256) void gemm1_kernel(const float* __restrict__ emb,
                             const int* __restrict__ xidx,
                             const float* __restrict__ W1,
                             unsigned short* __restrict__ h1b,
                             const float* __restrict__ a_s1, const float* __restrict__ a_d1,
                             float* __restrict__ as1, float* __restrict__ ad1, int N) {
    __shared__ float xs[64][128];
    __shared__ float ws[128][64];
    int tid = threadIdx.x;
    int r0 = blockIdx.x * 64;
    int c0 = blockIdx.y * 64;
    {
        const float4* W4 = (const float4*)W1;
        float4* ws4 = (float4*)ws;
        int cbase = c0 >> 2;
        for (int i = tid; i < 128 * 16; i += 256) {
            int k = i >> 4, c = i & 15;
            ws4[i] = W4[k * 32 + cbase + c];
        }
    }
    {
        float4* xs4 = (float4*)xs;
        for (int i = tid; i < 64 * 32; i += 256) {
            int r = i >> 5, c = i & 31;
            int row = r0 + r;
            float4 v = make_float4(0.f, 0.f, 0.f, 0.f);
            if (row < N) {
                int s = xidx[row];
                v = ((const float4*)emb)[(size_t)s * 32 + c];
            }
            xs4[i] = v;
        }
    }
    __syncthreads();
    int tr = tid >> 4;
    int tc = tid & 15;
    float4 acc[4];
    acc[0] = acc[1] = acc[2] = acc[3] = make_float4(0.f, 0.f, 0.f, 0.f);
    for (int k = 0; k < 128; k += 4) {
        float4 wv0 = *(const float4*)&ws[k][tc * 4];
        float4 wv1 = *(const float4*)&ws[k + 1][tc * 4];
        float4 wv2 = *(const float4*)&ws[k + 2][tc * 4];
        float4 wv3 = *(const float4*)&ws[k + 3][tc * 4];
#pragma unroll
        for (int i = 0; i < 4; i++) {
            float4 xv = *(const float4*)&xs[tr * 4 + i][k];
            acc[i].x = fmaf(xv.x, wv0.x, acc[i].x);
            acc[i].y = fmaf(xv.x, wv0.y, acc[i].y);
            acc[i].z = fmaf(xv.x, wv0.z, acc[i].z);
            acc[i].w = fmaf(xv.x, wv0.w, acc[i].w);
            acc[i].x = fmaf(xv.y, wv1.x, acc[i].x);
            acc[i].y = fmaf(xv.y, wv1.y, acc[i].y);
            acc[i].z = fmaf(xv.y, wv1.z, acc[i].z);
            acc[i].w = fmaf(xv.y, wv1.w, acc[i].w);
            acc[i].x = fmaf(xv.z, wv2.x, acc[i].x);
            acc[i].y = fmaf(xv.z, wv2.y, acc[i].y);
            acc[i].z = fmaf(xv.z, wv2.z, acc[i].z);
            acc[i].w = fmaf(xv.z, wv2.w, acc[i].w);
            acc[i].x = fmaf(xv.w, wv3.x, acc[i].x);
            acc[i].y = fmaf(xv.w, wv3.y, acc[i].y);
            acc[i].z = fmaf(xv.w, wv3.z, acc[i].z);
            acc[i].w = fmaf(xv.w, wv3.w, acc[i].w);
        }
    }
    int colbase = c0 + tc * 4;
    int h = colbase >> 5;
    int off = colbase & 31;
    float4 av = *(const float4*)&a_s1[h * 32 + off];
    float4 dv = *(const float4*)&a_d1[h * 32 + off];
#pragma unroll
    for (int i = 0; i < 4; i++) {
        int row = r0 + tr * 4 + i;
        if (row < N) {
            ushort4 pk;
            pk.x = f2bf(acc[i].x); pk.y = f2bf(acc[i].y);
            pk.z = f2bf(acc[i].z); pk.w = f2bf(acc[i].w);
            *(ushort4*)&h1b[(size_t)row * 128 + colbase] = pk;
        }
        float ps = dot4(acc[i], av);
        float pd = dot4(acc[i], dv);
        ps += __shfl_xor(ps, 1); pd += __shfl_xor(pd, 1);
        ps += __shfl_xor(ps, 2); pd += __shfl_xor(pd, 2);
        ps += __shfl_xor(ps, 4); pd += __shfl_xor(pd, 4);
        if ((tc & 7) == 0 && row < N) {
            as1[row * 4 + h] = ps;
            ad1[row * 4 + h] = pd;
        }
    }
}

// ---------------- gemm2 + fused alpha2 (h2 stays fp32) ----------------

__global__ __launch_bounds__(256) void gemm2_kernel(const float* __restrict__ x1,
                             const float* __restrict__ W2,
                             float* __restrict__ h2,
                             const float* __restrict__ a_s2, const float* __restrict__ a_d2,
                             float* __restrict__ as2, float* __restrict__ ad2, int N) {
    __shared__ float xs[64][128];
    __shared__ float ws[128][64];
    int tid = threadIdx.x;
    int r0 = blockIdx.x * 64;
    {
        const float4* W4 = (const float4*)W2;
        float4* ws4 = (float4*)ws;
        for (int i = tid; i < 128 * 16; i += 256) ws4[i] = W4[i];
    }
    {
        float4* xs4 = (float4*)xs;
        for (int i = tid; i < 64 * 32; i += 256) {
            int r = i >> 5, c = i & 31;
            int row = r0 + r;
            float4 v = make_float4(0.f, 0.f, 0.f, 0.f);
            if (row < N) v = ((const float4*)x1)[(size_t)row * 32 + c];
            xs4[i] = v;
        }
    }
    __syncthreads();
    int tr = tid >> 4;
    int tc = tid & 15;
    float4 acc[4];
    acc[0] = acc[1] = acc[2] = acc[3] = make_float4(0.f, 0.f, 0.f, 0.f);
    for (int k = 0; k < 128; k += 4) {
        float4 wv0 = *(const float4*)&ws[k][tc * 4];
        float4 wv1 = *(const float4*)&ws[k + 1][tc * 4];
        float4 wv2 = *(const float4*)&ws[k + 2][tc * 4];
        float4 wv3 = *(const float4*)&ws[k + 3][tc * 4];
#pragma unroll
        for (int i = 0; i < 4; i++) {
            float4 xv = *(const float4*)&xs[tr * 4 + i][k];
            acc[i].x = fmaf(xv.x, wv0.x, acc[i].x);
            acc[i].y = fmaf(xv.x, wv0.y, acc[i].y);
            acc[i].z = fmaf(xv.x, wv0.z, acc[i].z);
            acc[i].w = fmaf(xv.x, wv0.w, acc[i].w);
            acc[i].x = fmaf(xv.y, wv1.x, acc[i].x);
            acc[i].y = fmaf(xv.y, wv1.y, acc[i].y);
            acc[i].z = fmaf(xv.y, wv1.z, acc[i].z);
            acc[i].w = fmaf(xv.y, wv1.w, acc[i].w);
            acc[i].x = fmaf(xv.z, wv2.x, acc[i].x);
            acc[i].y = fmaf(xv.z, wv2.y, acc[i].y);
            acc[i].z = fmaf(xv.z, wv2.z, acc[i].z);
            acc[i].w = fmaf(xv.z, wv2.w, acc[i].w);
            acc[i].x = fmaf(xv.w, wv3.x, acc[i].x);
            acc[i].y = fmaf(xv.w, wv3.y, acc[i].y);
            acc[i].z = fmaf(xv.w, wv3.z, acc[i].z);
            acc[i].w = fmaf(xv.w, wv3.w, acc[i].w);
        }
    }
    float4 av = *(const float4*)&a_s2[tc * 4];
    float4 dv = *(const float4*)&a_d2[tc * 4];
#pragma unroll
    for (int i = 0; i < 4; i++) {
        int row = r0 + tr * 4 + i;
        if (row < N) *(float4*)&h2[(size_t)row * 64 + tc * 4] = acc[i];
        float ps = dot4(acc[i], av);
        float pd = dot4(acc[i], dv);
        ps += __shfl_xor(ps, 1); pd += __shfl_xor(pd, 1);
        ps += __shfl_xor(ps, 2); pd += __shfl_xor(pd, 2);
        ps += __shfl_xor(ps, 4); pd += __shfl_xor(pd, 4);
        ps += __shfl_xor(ps, 8); pd += __shfl_xor(pd, 8);
        if (tc == 0 && row < N) { as2[row] = ps; ad2[row] = pd; }
    }
}

// ---------------- aggregation: 4 edges per gather instruction ----------------

__device__ __forceinline__ void accum_group1(int srcReg, float4 wReg, int mcount,
                                             const uint4* __restrict__ h1v4,
                                             int sub, int cg, int hh, float* acc) {
    int b = 0;
    for (; b + 8 <= mcount; b += 8) {
        int i0 = b + sub, i1 = b + 4 + sub;
        int s0 = __shfl(srcReg, i0);
        int s1 = __shfl(srcReg, i1);
        float wx0 = __shfl(wReg.x, i0), wy0 = __shfl(wReg.y, i0);
        float wz0 = __shfl(wReg.z, i0), ww0 = __shfl(wReg.w, i0);
        float wx1 = __shfl(wReg.x, i1), wy1 = __shfl(wReg.y, i1);
        float wz1 = __shfl(wReg.z, i1), ww1 = __shfl(wReg.w, i1);
        uint4 u0 = h1v4[(size_t)s0 * 16 + cg];
        uint4 u1 = h1v4[(size_t)s1 * 16 + cg];
        float w_0 = (hh < 2) ? ((hh == 0) ? wx0 : wy0) : ((hh == 2) ? wz0 : ww0);
        float w_1 = (hh < 2) ? ((hh == 0) ? wx1 : wy1) : ((hh == 2) ? wz1 : ww1);
        acc[0] = fmaf(w_0, bflo(u0.x), acc[0]); acc[1] = fmaf(w_0, bfhi(u0.x), acc[1]);
        acc[2] = fmaf(w_0, bflo(u0.y), acc[2]); acc[3] = fmaf(w_0, bfhi(u0.y), acc[3]);
        acc[4] = fmaf(w_0, bflo(u0.z), acc[4]); acc[5] = fmaf(w_0, bfhi(u0.z), acc[5]);
        acc[6] = fmaf(w_0, bflo(u0.w), acc[6]); acc[7] = fmaf(w_0, bfhi(u0.w), acc[7]);
        acc[0] = fmaf(w_1, bflo(u1.x), acc[0]); acc[1] = fmaf(w_1, bfhi(u1.x), acc[1]);
        acc[2] = fmaf(w_1, bflo(u1.y), acc[2]); acc[3] = fmaf(w_1, bfhi(u1.y), acc[3]);
        acc[4] = fmaf(w_1, bflo(u1.z), acc[4]); acc[5] = fmaf(w_1, bfhi(u1.z), acc[5]);
        acc[6] = fmaf(w_1, bflo(u1.w), acc[6]); acc[7] = fmaf(w_1, bfhi(u1.w), acc[7]);
    }
    for (; b + 4 <= mcount; b += 4) {
        int i0 = b + sub;
        int s0 = __shfl(srcReg, i0);
        float wx = __shfl(wReg.x, i0), wy = __shfl(wReg.y, i0);
        float wz = __shfl(wReg.z, i0), ww = __shfl(wReg.w, i0);
        uint4 u0 = h1v4[(size_t)s0 * 16 + cg];
        float w = (hh < 2) ? ((hh == 0) ? wx : wy) : ((hh == 2) ? wz : ww);
        acc[0] = fmaf(w, bflo(u0.x), acc[0]); acc[1] = fmaf(w, bfhi(u0.x), acc[1]);
        acc[2] = fmaf(w, bflo(u0.y), acc[2]); acc[3] = fmaf(w, bfhi(u0.y), acc[3]);
        acc[4] = fmaf(w, bflo(u0.z), acc[4]); acc[5] = fmaf(w, bfhi(u0.z), acc[5]);
        acc[6] = fmaf(w, bflo(u0.w), acc[6]); acc[7] = fmaf(w, bfhi(u0.w), acc[7]);
    }
    if (b < mcount) {
        int rem = mcount - b;
        int i0 = b + sub;
        int s0 = __shfl(srcReg, i0);
        float wx = __shfl(wReg.x, i0), wy = __shfl(wReg.y, i0);
        float wz = __shfl(wReg.z, i0), ww = __shfl(wReg.w, i0);
        if (sub < rem) {
            uint4 u0 = h1v4[(size_t)s0 * 16 + cg];
            float w = (hh < 2) ? ((hh == 0) ? wx : wy) : ((hh == 2) ? wz : ww);
            acc[0] = fmaf(w, bflo(u0.x), acc[0]); acc[1] = fmaf(w, bfhi(u0.x), acc[1]);
            acc[2] = fmaf(w, bflo(u0.y), acc[2]); acc[3] = fmaf(w, bfhi(u0.y), acc[3]);
            acc[4] = fmaf(w, bflo(u0.z), acc[4]); acc[5] = fmaf(w, bfhi(u0.z), acc[5]);
            acc[6] = fmaf(w, bflo(u0.w), acc[6]); acc[7] = fmaf(w, bfhi(u0.w), acc[7]);
        }
    }
}

__global__ void __launch_bounds__(256)
agg1_kernel(const int* __restrict__ csr, const int* __restrict__ indptr,
            const int* __restrict__ counts, const float* __restrict__ as1,
            const float* __restrict__ ad1, const unsigned short* __restrict__ h1b,
            const float* __restrict__ b1, float* __restrict__ x1, int N) {
    int lane = threadIdx.x & 63;
    int n = blockIdx.x * 4 + (threadIdx.x >> 6);
    if (n >= N) return;
    int start = indptr[n];
    int cnt = counts[n];
    float4 ad4 = ((const float4*)ad1)[n];

    int src0 = 0;
    float4 e0 = make_float4(-1e30f, -1e30f, -1e30f, -1e30f);
    if (lane < cnt) {
        src0 = csr[start + lane];
        float4 a = ((const float4*)as1)[src0];
        e0.x = leaky(a.x + ad4.x);
        e0.y = leaky(a.y + ad4.y);
        e0.z = leaky(a.z + ad4.z);
        e0.w = leaky(a.w + ad4.w);
    }
    float4 m4 = e0;
#pragma unroll
    for (int off = 32; off >= 1; off >>= 1) {
        m4.x = fmaxf(m4.x, __shfl_xor(m4.x, off));
        m4.y = fmaxf(m4.y, __shfl_xor(m4.y, off));
        m4.z = fmaxf(m4.z, __shfl_xor(m4.z, off));
        m4.w = fmaxf(m4.w, __shfl_xor(m4.w, off));
    }
    if (cnt > 64) {
        for (int base = 64; base < cnt; base += 64) {
            float4 e = make_float4(-1e30f, -1e30f, -1e30f, -1e30f);
            if (base + lane < cnt) {
                int s = csr[start + base + lane];
                float4 a = ((const float4*)as1)[s];
                e.x = leaky(a.x + ad4.x); e.y = leaky(a.y + ad4.y);
                e.z = leaky(a.z + ad4.z); e.w = leaky(a.w + ad4.w);
            }
#pragma unroll
            for (int off = 32; off >= 1; off >>= 1) {
                e.x = fmaxf(e.x, __shfl_xor(e.x, off));
                e.y = fmaxf(e.y, __shfl_xor(e.y, off));
                e.z = fmaxf(e.z, __shfl_xor(e.z, off));
                e.w = fmaxf(e.w, __shfl_xor(e.w, off));
            }
            m4.x = fmaxf(m4.x, e.x); m4.y = fmaxf(m4.y, e.y);
            m4.z = fmaxf(m4.z, e.z); m4.w = fmaxf(m4.w, e.w);
        }
    }
    float4 p0;
    p0.x = __expf(e0.x - m4.x);
    p0.y = __expf(e0.y - m4.y);
    p0.z = __expf(e0.z - m4.z);
    p0.w = __expf(e0.w - m4.w);
    float4 l4 = p0;
#pragma unroll
    for (int off = 32; off >= 1; off >>= 1) {
        l4.x += __shfl_xor(l4.x, off);
        l4.y += __shfl_xor(l4.y, off);
        l4.z += __shfl_xor(l4.z, off);
        l4.w += __shfl_xor(l4.w, off);
    }
    if (cnt > 64) {
        for (int base = 64; base < cnt; base += 64) {
            float4 p = make_float4(0.f, 0.f, 0.f, 0.f);
            if (base + lane < cnt) {
                int s = csr[start + base + lane];
                float4 a = ((const float4*)as1)[s];
                p.x = __expf(leaky(a.x + ad4.x) - m4.x);
                p.y = __expf(leaky(a.y + ad4.y) - m4.y);
                p.z = __expf(leaky(a.z + ad4.z) - m4.z);
                p.w = __expf(leaky(a.w + ad4.w) - m4.w);
            }
#pragma unroll
            for (int off = 32; off >= 1; off >>= 1) {
                p.x += __shfl_xor(p.x, off);
                p.y += __shfl_xor(p.y, off);
                p.z += __shfl_xor(p.z, off);
                p.w += __shfl_xor(p.w, off);
            }
            l4.x += p.x; l4.y += p.y; l4.z += p.z; l4.w += p.w;
        }
    }
    float4 li = make_float4(1.f / l4.x, 1.f / l4.y, 1.f / l4.z, 1.f / l4.w);
    float4 w0 = make_float4(p0.x * li.x, p0.y * li.y, p0.z * li.z, p0.w * li.w);

    int sub = lane >> 4;
    int cg = lane & 15;
    int hh = cg >> 2;
    const uint4* h1v4 = (const uint4*)h1b;
    float acc[8] = {0.f, 0.f, 0.f, 0.f, 0.f, 0.f, 0.f, 0.f};
    accum_group1(src0, w0, min(cnt, 64), h1v4, sub, cg, hh, acc);
    if (cnt > 64) {
        for (int base = 64; base < cnt; base += 64) {
            int srcc = 0;
            float4 wc = make_float4(0.f, 0.f, 0.f, 0.f);
            if (base + lane < cnt) {
                srcc = csr[start + base + lane];
                float4 a = ((const float4*)as1)[srcc];
                wc.x = __expf(leaky(a.x + ad4.x) - m4.x) * li.x;
                wc.y = __expf(leaky(a.y + ad4.y) - m4.y) * li.y;
                wc.z = __expf(leaky(a.z + ad4.z) - m4.z) * li.z;
                wc.w = __expf(leaky(a.w + ad4.w) - m4.w) * li.w;
            }
            accum_group1(srcc, wc, min(cnt - base, 64), h1v4, sub, cg, hh, acc);
        }
    }
#pragma unroll
    for (int i = 0; i < 8; i++) {
        acc[i] += __shfl_xor(acc[i], 16);
        acc[i] += __shfl_xor(acc[i], 32);
    }
    if (lane < 16) {
        float4 o0, o1;
        const float4* b4 = (const float4*)b1;
        float4 ba = b4[cg * 2], bb = b4[cg * 2 + 1];
        o0.x = acc[0] + ba.x; o0.y = acc[1] + ba.y; o0.z = acc[2] + ba.z; o0.w = acc[3] + ba.w;
        o1.x = acc[4] + bb.x; o1.y = acc[5] + bb.y; o1.z = acc[6] + bb.z; o1.w = acc[7] + bb.w;
        o0.x = (o0.x > 0.f) ? o0.x : (__expf(o0.x) - 1.f);
        o0.y = (o0.y > 0.f) ? o0.y : (__expf(o0.y) - 1.f);
        o0.z = (o0.z > 0.f) ? o0.z : (__expf(o0.z) - 1.f);
        o0.w = (o0.w > 0.f) ? o0.w : (__expf(o0.w) - 1.f);
        o1.x = (o1.x > 0.f) ? o1.x : (__expf(o1.x) - 1.f);
        o1.y = (o1.y > 0.f) ? o1.y : (__expf(o1.y) - 1.f);
        o1.z = (o1.z > 0.f) ? o1.z : (__expf(o1.z) - 1.f);
        o1.w = (o1.w > 0.f) ? o1.w : (__expf(o1.w) - 1.f);
        float4* xrow = (float4*)&x1[(size_t)n * 128 + cg * 8];
        xrow[0] = o0;
        xrow[1] = o1;
    }
}

__device__ __forceinline__ void accum_group2(int srcReg, float wReg, int mcount,
                                             const float4* __restrict__ h2v4,
                                             int sub, int cg, float4* acc) {
    int b = 0;
    for (; b + 8 <= mcount; b += 8) {
        int i0 = b + sub, i1 = b + 4 + sub;
        int s0 = __shfl(srcReg, i0);
        int s1 = __shfl(srcReg, i1);
        float w_0 = __shfl(wReg, i0);
        float w_1 = __shfl(wReg, i1);
        float4 v0 = h2v4[(size_t)s0 * 16 + cg];
        float4 v1 = h2v4[(size_t)s1 * 16 + cg];
        acc->x = fmaf(w_0, v0.x, acc->x); acc->y = fmaf(w_0, v0.y, acc->y);
        acc->z = fmaf(w_0, v0.z, acc->z); acc->w = fmaf(w_0, v0.w, acc->w);
        acc->x = fmaf(w_1, v1.x, acc->x); acc->y = fmaf(w_1, v1.y, acc->y);
        acc->z = fmaf(w_1, v1.z, acc->z); acc->w = fmaf(w_1, v1.w, acc->w);
    }
    for (; b + 4 <= mcount; b += 4) {
        int i0 = b + sub;
        int s0 = __shfl(srcReg, i0);
        float w_0 = __shfl(wReg, i0);
        float4 v0 = h2v4[(size_t)s0 * 16 + cg];
        acc->x = fmaf(w_0, v0.x, acc->x); acc->y = fmaf(w_0, v0.y, acc->y);
        acc->z = fmaf(w_0, v0.z, acc->z); acc->w = fmaf(w_0, v0.w, acc->w);
    }
    if (b < mcount) {
        int rem = mcount - b;
        int i0 = b + sub;
        int s0 = __shfl(srcReg, i0);
        float w_0 = __shfl(wReg, i0);
        if (sub < rem) {
            float4 v0 = h2v4[(size_t)s0 * 16 + cg];
            acc->x = fmaf(w_0, v0.x, acc->x); acc->y = fmaf(w_0, v0.y, acc->y);
            acc->z = fmaf(w_0, v0.z, acc->z); acc->w = fmaf(w_0, v0.w, acc->w);
        }
    }
}

__global__ void __launch_bounds__(256)
agg2_kernel(const int* __restrict__ csr, const int* __restrict__ indptr,
            const int* __restrict__ counts, const float* __restrict__ as2,
            const float* __restrict__ ad2, const float* __restrict__ h2,
            const float* __restrict__ b2, float* __restrict__ out, int N) {
    int lane = threadIdx.x & 63;
    int n = blockIdx.x * 4 + (threadIdx.x >> 6);
    if (n >= N) return;
    int start = indptr[n];
    int cnt = counts[n];
    float ad = ad2[n];

    int src0 = 0;
    float e0 = -1e30f;
    if (lane < cnt) {
        src0 = csr[start + lane];
        e0 = leaky(as2[src0] + ad);
    }
    float m = e0;
#pragma unroll
    for (int off = 32; off >= 1; off >>= 1) m = fmaxf(m, __shfl_xor(m, off));
    if (cnt > 64) {
        for (int base = 64; base < cnt; base += 64) {
            float e = -1e30f;
            if (base + lane < cnt) e = leaky(as2[csr[start + base + lane]] + ad);
#pragma unroll
            for (int off = 32; off >= 1; off >>= 1) e = fmaxf(e, __shfl_xor(e, off));
            m = fmaxf(m, e);
        }
    }
    float p0 = __expf(e0 - m);
    float l = p0;
#pragma unroll
    for (int off = 32; off >= 1; off >>= 1) l += __shfl_xor(l, off);
    if (cnt > 64) {
        for (int base = 64; base < cnt; base += 64) {
            float p = 0.f;
            if (base + lane < cnt) p = __expf(leaky(as2[csr[start + base + lane]] + ad) - m);
#pragma unroll
            for (int off = 32; off >= 1; off >>= 1) p += __shfl_xor(p, off);
            l += p;
        }
    }
    float li = 1.f / l;
    float w0 = p0 * li;

    int sub = lane >> 4;
    int cg = lane & 15;
    const float4* h2v4 = (const float4*)h2;
    float4 acc = make_float4(0.f, 0.f, 0.f, 0.f);
    accum_group2(src0, w0, min(cnt, 64), h2v4, sub, cg, &acc);
    if (cnt > 64) {
        for (int base = 64; base < cnt; base += 64) {
            int srcc = 0;
            float wc = 0.f;
            if (base + lane < cnt) {
                srcc = csr[start + base + lane];
                wc = __expf(leaky(as2[srcc] + ad) - m) * li;
            }
            accum_group2(srcc, wc, min(cnt - base, 64), h2v4, sub, cg, &acc);
        }
    }
    acc.x += __shfl_xor(acc.x, 16); acc.x += __shfl_xor(acc.x, 32);
    acc.y += __shfl_xor(acc.y, 16); acc.y += __shfl_xor(acc.y, 32);
    acc.z += __shfl_xor(acc.z, 16); acc.z += __shfl_xor(acc.z, 32);
    acc.w += __shfl_xor(acc.w, 16); acc.w += __shfl_xor(acc.w, 32);
    if (lane < 16) {
        float4 b = ((const float4*)b2)[cg];
        float4 o;
        o.x = acc.x + b.x; o.y = acc.y + b.y; o.z = acc.z + b.z; o.w = acc.w + b.w;
        ((float4*)out)[(size_t)n * 16 + cg] = o;
    }
}

// ---------------- launcher ----------------

extern "C" void kernel_launch(void* const* d_in, const int* in_sizes, int n_in,
                              void* d_out, int out_size, void* d_ws, size_t ws_size,
                              hipStream_t stream) {
    const int*   xidx = (const int*)d_in[0];
    const int*   ei   = (const int*)d_in[1];
    const float* emb  = (const float*)d_in[2];
    const float* W1   = (const float*)d_in[3];
    const float* a_s1 = (const float*)d_in[4];
    const float* a_d1 = (const float*)d_in[5];
    const float* b1   = (const float*)d_in[6];
    const float* W2   = (const float*)d_in[7];
    const float* a_s2 = (const float*)d_in[8];
    const float* a_d2 = (const float*)d_in[9];
    const float* b2   = (const float*)d_in[10];
    float* out = (float*)d_out;

    const int N  = in_sizes[0];
    const int E  = in_sizes[1] / 2;
    const int E2 = E + N;
    const int K  = (N + 255) >> BK_SHIFT;   // 391 buckets for N=100000 (K <= 512 required)

    // workspace layout
    int* ws_i    = (int*)d_ws;
    int* counts  = ws_i;                       // N
    int* indptr  = ws_i + N;                   // N
    int* bcounts = ws_i + 2 * (size_t)N;       // 512
    int* bbase   = ws_i + 2 * (size_t)N + 512; // 513
    int* bcursor = ws_i + 2 * (size_t)N + 1032;// 512
    int* csr     = ws_i + 2 * (size_t)N + 1544;// E2
    size_t fbase = ((size_t)(2 * (size_t)N + 1544 + E2) + 3) & ~(size_t)3;
    float* ws_f = (float*)d_ws;
    unsigned short* h1b = (unsigned short*)(ws_f + fbase);   // N*128 bf16
    float* x1  = ws_f + fbase + (size_t)N * 64;              // N*128 floats
    float* as1 = x1 + (size_t)N * 128;                       // N*4
    float* ad1 = as1 + (size_t)N * 4;                        // N*4
    float* h2  = (float*)h1b;     // alias: h1b dead after agg1
    float* as2 = as1;             // alias
    float* ad2 = ad1;
    uint2* bedges = (uint2*)x1;   // alias: bedges (E2*8B) dead before agg1 writes x1

    // CSR build: dst-radix partition
    int nchunks = (E2 + 4095) / 4096;
    zero_kernel<<<(K + 255) / 256, 256, 0, stream>>>(bcounts, K);
    bcount_kernel<<<nchunks, 256, 0, stream>>>(ei, E, E2, K, bcounts);
    bscan_kernel<<<1, 512, 0, stream>>>(bcounts, K, bbase, bcursor);
    bscatter_kernel<<<nchunks, 256, 0, stream>>>(ei, E, E2, K, bcursor, bedges);
    bcsr_kernel<<<K, 256, 0, stream>>>(bedges, bbase, N, counts, indptr, csr);

    // Layer 1 (gemm1 fuses alpha1 + bf16 h1)
    {
        dim3 g((N + 63) / 64, 2);
        gemm1_kernel<<<g, 256, 0, stream>>>(emb, xidx, W1, h1b, a_s1, a_d1, as1, ad1, N);
    }
    agg1_kernel<<<(N + 3) / 4, 256, 0, stream>>>(csr, indptr, counts, as1, ad1, h1b, b1, x1, N);

    // Layer 2 (gemm2 fuses alpha2)
    gemm2_kernel<<<(N + 63) / 64, 256, 0, stream>>>(x1, W2, h2, a_s2, a_d2, as2, ad2, N);
    agg2_kernel<<<(N + 3) / 4, 256, 0, stream>>>(csr, indptr, counts, as2, ad2, h2, b2, out, N);
}

// Round 8
// 443.840 us; speedup vs baseline: 1.4666x; 1.0710x over previous
//
#include <hip/hip_runtime.h>
#include <math.h>

// GATNet: N=100000 nodes, D=128, HEADS=4, HID=32, OUT_C=64, E=1.6M (+N self-loops)
#define NEG_SLOPE 0.2f
#define BK_SHIFT 8          // bucket = dst >> 8 (256 dsts per bucket)

__device__ __forceinline__ float leaky(float x) { return x > 0.f ? x : NEG_SLOPE * x; }
__device__ __forceinline__ float dot4(float4 a, float4 b) {
    return a.x * b.x + a.y * b.y + a.z * b.z + a.w * b.w;
}
// fp32 -> bf16 round-to-nearest-even
__device__ __forceinline__ unsigned short f2bf(float f) {
    unsigned int x = __float_as_uint(f);
    unsigned int r = (x + 0x7fffu + ((x >> 16) & 1u)) >> 16;
    return (unsigned short)r;
}
__device__ __forceinline__ float bflo(unsigned int u) { return __uint_as_float(u << 16); }
__device__ __forceinline__ float bfhi(unsigned int u) { return __uint_as_float(u & 0xffff0000u); }

// ---------------- CSR build: dst-radix partition ----------------

__global__ void zero_kernel(int* __restrict__ p, int n) {
    int i = blockIdx.x * blockDim.x + threadIdx.x;
    if (i < n) p[i] = 0;
}

__global__ void __launch_bounds__(256) bcount_kernel(const int* __restrict__ ei, int E, int E2,
                                                     int K, int* __restrict__ bcounts) {
    __shared__ int h[512];
    int t = threadIdx.x;
    h[t] = 0; h[t + 256] = 0;
    __syncthreads();
    int base = blockIdx.x * 4096;
#pragma unroll 4
    for (int i = 0; i < 16; i++) {
        int e = base + i * 256 + t;
        if (e < E2) {
            int dst = (e < E) ? ei[E + e] : (e - E);
            atomicAdd(&h[dst >> BK_SHIFT], 1);
        }
    }
    __syncthreads();
    for (int b = t; b < K; b += 256) {
        int c = h[b];
        if (c) atomicAdd(&bcounts[b], c);
    }
}

__global__ void __launch_bounds__(512) bscan_kernel(const int* __restrict__ bcounts, int K,
                                                    int* __restrict__ bbase, int* __restrict__ bcursor) {
    __shared__ int s[512];
    int t = threadIdx.x;
    int v = (t < K) ? bcounts[t] : 0;
    s[t] = v;
    __syncthreads();
    for (int off = 1; off < 512; off <<= 1) {
        int u = (t >= off) ? s[t - off] : 0;
        __syncthreads();
        s[t] += u;
        __syncthreads();
    }
    if (t < K) {
        int ex = s[t] - v;
        bbase[t] = ex;
        bcursor[t] = ex;
    }
    if (t == 511) bbase[K] = s[511];
}

__global__ void __launch_bounds__(256) bscatter_kernel(const int* __restrict__ ei, int E, int E2,
                                                       int K, int* __restrict__ bcursor,
                                                       uint2* __restrict__ bedges) {
    __shared__ int hist[512], pre[512], lcur[512], gbase[512], psum[256];
    __shared__ uint2 stage[4096];
    int t = threadIdx.x;
    hist[t] = 0; hist[t + 256] = 0;
    __syncthreads();
    int base = blockIdx.x * 4096;
    int cnt = min(4096, E2 - base);
    int s_[16], d_[16];
#pragma unroll
    for (int i = 0; i < 16; i++) {
        int e = base + i * 256 + t;
        if (e < E2) {
            int ss, dd;
            if (e < E) { ss = ei[e]; dd = ei[E + e]; }
            else       { ss = e - E; dd = ss; }
            s_[i] = ss; d_[i] = dd;
            atomicAdd(&hist[dd >> BK_SHIFT], 1);
        }
    }
    __syncthreads();
    int a0 = hist[2 * t], a1 = hist[2 * t + 1];
    psum[t] = a0 + a1;
    __syncthreads();
    for (int off = 1; off < 256; off <<= 1) {
        int u = (t >= off) ? psum[t - off] : 0;
        __syncthreads();
        psum[t] += u;
        __syncthreads();
    }
    int pex = psum[t] - (a0 + a1);
    pre[2 * t] = pex;
    pre[2 * t + 1] = pex + a0;
    __syncthreads();
    for (int b = t; b < K; b += 256) {
        int c = hist[b];
        if (c) gbase[b] = atomicAdd(&bcursor[b], c);
    }
    lcur[t] = pre[t]; lcur[t + 256] = pre[t + 256];
    __syncthreads();
#pragma unroll
    for (int i = 0; i < 16; i++) {
        int e = base + i * 256 + t;
        if (e < E2) {
            int bin = d_[i] >> BK_SHIFT;
            int p = atomicAdd(&lcur[bin], 1);
            stage[p] = make_uint2((unsigned)s_[i], (unsigned)d_[i]);
        }
    }
    __syncthreads();
    for (int i = t; i < cnt; i += 256) {
        uint2 ed = stage[i];
        int bin = (int)(ed.y >> BK_SHIFT);
        bedges[gbase[bin] + (i - pre[bin])] = ed;
    }
}

__global__ void __launch_bounds__(256) bcsr_kernel(const uint2* __restrict__ bedges,
                                                   const int* __restrict__ bbase, int N,
                                                   int* __restrict__ counts, int* __restrict__ indptr,
                                                   int* __restrict__ csr) {
    __shared__ int hist[256], scn[256], cur[256];
    int b = blockIdx.x;
    int t = threadIdx.x;
    int base = bbase[b];
    int cnt = bbase[b + 1] - base;
    hist[t] = 0;
    __syncthreads();
    for (int i = t; i < cnt; i += 256) {
        atomicAdd(&hist[bedges[base + i].y & 255], 1);
    }
    __syncthreads();
    int v = hist[t];
    scn[t] = v;
    __syncthreads();
    for (int off = 1; off < 256; off <<= 1) {
        int u = (t >= off) ? scn[t - off] : 0;
        __syncthreads();
        scn[t] += u;
        __syncthreads();
    }
    int ex = scn[t] - v;
    int d = (b << BK_SHIFT) + t;
    if (d < N) { counts[d] = v; indptr[d] = base + ex; }
    cur[t] = ex;
    __syncthreads();
    for (int i = t; i < cnt; i += 256) {
        uint2 ed = bedges[base + i];
        int p = atomicAdd(&cur[ed.y & 255], 1);
        csr[base + p] = (int)ed.x;
    }
}

// ---------------- gemm1 + fused alpha1, bf16 h1 output ----------------

__global__ __launch_bounds__(256) void gemm1_kernel(const float* __restrict__ emb,
                             const int* __restrict__ xidx,
                             const float* __restrict__ W1,
                             unsigned short* __restrict__ h1b,
                             const float* __restrict__ a_s1, const float* __restrict__ a_d1,
                             float* __restrict__ as1, float* __restrict__ ad1, int N) {
    __shared__ float xs[64][128];
    __shared__ float ws[128][64];
    int tid = threadIdx.x;
    int r0 = blockIdx.x * 64;
    int c0 = blockIdx.y * 64;
    {
        const float4* W4 = (const float4*)W1;
        float4* ws4 = (float4*)ws;
        int cbase = c0 >> 2;
        for (int i = tid; i < 128 * 16; i += 256) {
            int k = i >> 4, c = i & 15;
            ws4[i] = W4[k * 32 + cbase + c];
        }
    }
    {
        float4* xs4 = (float4*)xs;
        for (int i = tid; i < 64 * 32; i += 256) {
            int r = i >> 5, c = i & 31;
            int row = r0 + r;
            float4 v = make_float4(0.f, 0.f, 0.f, 0.f);
            if (row < N) {
                int s = xidx[row];
                v = ((const float4*)emb)[(size_t)s * 32 + c];
            }
            xs4[i] = v;
        }
    }
    __syncthreads();
    int tr = tid >> 4;
    int tc = tid & 15;
    float4 acc[4];
    acc[0] = acc[1] = acc[2] = acc[3] = make_float4(0.f, 0.f, 0.f, 0.f);
    for (int k = 0; k < 128; k += 4) {
        float4 wv0 = *(const float4*)&ws[k][tc * 4];
        float4 wv1 = *(const float4*)&ws[k + 1][tc * 4];
        float4 wv2 = *(const float4*)&ws[k + 2][tc * 4];
        float4 wv3 = *(const float4*)&ws[k + 3][tc * 4];
#pragma unroll
        for (int i = 0; i < 4; i++) {
            float4 xv = *(const float4*)&xs[tr * 4 + i][k];
            acc[i].x = fmaf(xv.x, wv0.x, acc[i].x);
            acc[i].y = fmaf(xv.x, wv0.y, acc[i].y);
            acc[i].z = fmaf(xv.x, wv0.z, acc[i].z);
            acc[i].w = fmaf(xv.x, wv0.w, acc[i].w);
            acc[i].x = fmaf(xv.y, wv1.x, acc[i].x);
            acc[i].y = fmaf(xv.y, wv1.y, acc[i].y);
            acc[i].z = fmaf(xv.y, wv1.z, acc[i].z);
            acc[i].w = fmaf(xv.y, wv1.w, acc[i].w);
            acc[i].x = fmaf(xv.z, wv2.x, acc[i].x);
            acc[i].y = fmaf(xv.z, wv2.y, acc[i].y);
            acc[i].z = fmaf(xv.z, wv2.z, acc[i].z);
            acc[i].w = fmaf(xv.z, wv2.w, acc[i].w);
            acc[i].x = fmaf(xv.w, wv3.x, acc[i].x);
            acc[i].y = fmaf(xv.w, wv3.y, acc[i].y);
            acc[i].z = fmaf(xv.w, wv3.z, acc[i].z);
            acc[i].w = fmaf(xv.w, wv3.w, acc[i].w);
        }
    }
    int colbase = c0 + tc * 4;
    int h = colbase >> 5;
    int off = colbase & 31;
    float4 av = *(const float4*)&a_s1[h * 32 + off];
    float4 dv = *(const float4*)&a_d1[h * 32 + off];
#pragma unroll
    for (int i = 0; i < 4; i++) {
        int row = r0 + tr * 4 + i;
        if (row < N) {
            ushort4 pk;
            pk.x = f2bf(acc[i].x); pk.y = f2bf(acc[i].y);
            pk.z = f2bf(acc[i].z); pk.w = f2bf(acc[i].w);
            *(ushort4*)&h1b[(size_t)row * 128 + colbase] = pk;
        }
        float ps = dot4(acc[i], av);
        float pd = dot4(acc[i], dv);
        ps += __shfl_xor(ps, 1); pd += __shfl_xor(pd, 1);
        ps += __shfl_xor(ps, 2); pd += __shfl_xor(pd, 2);
        ps += __shfl_xor(ps, 4); pd += __shfl_xor(pd, 4);
        if ((tc & 7) == 0 && row < N) {
            as1[row * 4 + h] = ps;
            ad1[row * 4 + h] = pd;
        }
    }
}

// ---------------- gemm2 + fused alpha2, bf16 h2 output ----------------

__global__ __launch_bounds__(256) void gemm2_kernel(const float* __restrict__ x1,
                             const float* __restrict__ W2,
                             unsigned short* __restrict__ h2b,
                             const float* __restrict__ a_s2, const float* __restrict__ a_d2,
                             float* __restrict__ as2, float* __restrict__ ad2, int N) {
    __shared__ float xs[64][128];
    __shared__ float ws[128][64];
    int tid = threadIdx.x;
    int r0 = blockIdx.x * 64;
    {
        const float4* W4 = (const float4*)W2;
        float4* ws4 = (float4*)ws;
        for (int i = tid; i < 128 * 16; i += 256) ws4[i] = W4[i];
    }
    {
        float4* xs4 = (float4*)xs;
        for (int i = tid; i < 64 * 32; i += 256) {
            int r = i >> 5, c = i & 31;
            int row = r0 + r;
            float4 v = make_float4(0.f, 0.f, 0.f, 0.f);
            if (row < N) v = ((const float4*)x1)[(size_t)row * 32 + c];
            xs4[i] = v;
        }
    }
    __syncthreads();
    int tr = tid >> 4;
    int tc = tid & 15;
    float4 acc[4];
    acc[0] = acc[1] = acc[2] = acc[3] = make_float4(0.f, 0.f, 0.f, 0.f);
    for (int k = 0; k < 128; k += 4) {
        float4 wv0 = *(const float4*)&ws[k][tc * 4];
        float4 wv1 = *(const float4*)&ws[k + 1][tc * 4];
        float4 wv2 = *(const float4*)&ws[k + 2][tc * 4];
        float4 wv3 = *(const float4*)&ws[k + 3][tc * 4];
#pragma unroll
        for (int i = 0; i < 4; i++) {
            float4 xv = *(const float4*)&xs[tr * 4 + i][k];
            acc[i].x = fmaf(xv.x, wv0.x, acc[i].x);
            acc[i].y = fmaf(xv.x, wv0.y, acc[i].y);
            acc[i].z = fmaf(xv.x, wv0.z, acc[i].z);
            acc[i].w = fmaf(xv.x, wv0.w, acc[i].w);
            acc[i].x = fmaf(xv.y, wv1.x, acc[i].x);
            acc[i].y = fmaf(xv.y, wv1.y, acc[i].y);
            acc[i].z = fmaf(xv.y, wv1.z, acc[i].z);
            acc[i].w = fmaf(xv.y, wv1.w, acc[i].w);
            acc[i].x = fmaf(xv.z, wv2.x, acc[i].x);
            acc[i].y = fmaf(xv.z, wv2.y, acc[i].y);
            acc[i].z = fmaf(xv.z, wv2.z, acc[i].z);
            acc[i].w = fmaf(xv.z, wv2.w, acc[i].w);
            acc[i].x = fmaf(xv.w, wv3.x, acc[i].x);
            acc[i].y = fmaf(xv.w, wv3.y, acc[i].y);
            acc[i].z = fmaf(xv.w, wv3.z, acc[i].z);
            acc[i].w = fmaf(xv.w, wv3.w, acc[i].w);
        }
    }
    float4 av = *(const float4*)&a_s2[tc * 4];
    float4 dv = *(const float4*)&a_d2[tc * 4];
#pragma unroll
    for (int i = 0; i < 4; i++) {
        int row = r0 + tr * 4 + i;
        if (row < N) {
            ushort4 pk;
            pk.x = f2bf(acc[i].x); pk.y = f2bf(acc[i].y);
            pk.z = f2bf(acc[i].z); pk.w = f2bf(acc[i].w);
            *(ushort4*)&h2b[(size_t)row * 64 + tc * 4] = pk;
        }
        float ps = dot4(acc[i], av);
        float pd = dot4(acc[i], dv);
        ps += __shfl_xor(ps, 1); pd += __shfl_xor(pd, 1);
        ps += __shfl_xor(ps, 2); pd += __shfl_xor(pd, 2);
        ps += __shfl_xor(ps, 4); pd += __shfl_xor(pd, 4);
        ps += __shfl_xor(ps, 8); pd += __shfl_xor(pd, 8);
        if (tc == 0 && row < N) { as2[row] = ps; ad2[row] = pd; }
    }
}

// ---------------- aggregation layer 1: 4 edges per gather (bf16 rows) ----------------

__device__ __forceinline__ void accum_group1(int srcReg, float4 wReg, int mcount,
                                             const uint4* __restrict__ h1v4,
                                             int sub, int cg, int hh, float* acc) {
    int b = 0;
    for (; b + 8 <= mcount; b += 8) {
        int i0 = b + sub, i1 = b + 4 + sub;
        int s0 = __shfl(srcReg, i0);
        int s1 = __shfl(srcReg, i1);
        float wx0 = __shfl(wReg.x, i0), wy0 = __shfl(wReg.y, i0);
        float wz0 = __shfl(wReg.z, i0), ww0 = __shfl(wReg.w, i0);
        float wx1 = __shfl(wReg.x, i1), wy1 = __shfl(wReg.y, i1);
        float wz1 = __shfl(wReg.z, i1), ww1 = __shfl(wReg.w, i1);
        uint4 u0 = h1v4[(size_t)s0 * 16 + cg];
        uint4 u1 = h1v4[(size_t)s1 * 16 + cg];
        float w_0 = (hh < 2) ? ((hh == 0) ? wx0 : wy0) : ((hh == 2) ? wz0 : ww0);
        float w_1 = (hh < 2) ? ((hh == 0) ? wx1 : wy1) : ((hh == 2) ? wz1 : ww1);
        acc[0] = fmaf(w_0, bflo(u0.x), acc[0]); acc[1] = fmaf(w_0, bfhi(u0.x), acc[1]);
        acc[2] = fmaf(w_0, bflo(u0.y), acc[2]); acc[3] = fmaf(w_0, bfhi(u0.y), acc[3]);
        acc[4] = fmaf(w_0, bflo(u0.z), acc[4]); acc[5] = fmaf(w_0, bfhi(u0.z), acc[5]);
        acc[6] = fmaf(w_0, bflo(u0.w), acc[6]); acc[7] = fmaf(w_0, bfhi(u0.w), acc[7]);
        acc[0] = fmaf(w_1, bflo(u1.x), acc[0]); acc[1] = fmaf(w_1, bfhi(u1.x), acc[1]);
        acc[2] = fmaf(w_1, bflo(u1.y), acc[2]); acc[3] = fmaf(w_1, bfhi(u1.y), acc[3]);
        acc[4] = fmaf(w_1, bflo(u1.z), acc[4]); acc[5] = fmaf(w_1, bfhi(u1.z), acc[5]);
        acc[6] = fmaf(w_1, bflo(u1.w), acc[6]); acc[7] = fmaf(w_1, bfhi(u1.w), acc[7]);
    }
    for (; b + 4 <= mcount; b += 4) {
        int i0 = b + sub;
        int s0 = __shfl(srcReg, i0);
        float wx = __shfl(wReg.x, i0), wy = __shfl(wReg.y, i0);
        float wz = __shfl(wReg.z, i0), ww = __shfl(wReg.w, i0);
        uint4 u0 = h1v4[(size_t)s0 * 16 + cg];
        float w = (hh < 2) ? ((hh == 0) ? wx : wy) : ((hh == 2) ? wz : ww);
        acc[0] = fmaf(w, bflo(u0.x), acc[0]); acc[1] = fmaf(w, bfhi(u0.x), acc[1]);
        acc[2] = fmaf(w, bflo(u0.y), acc[2]); acc[3] = fmaf(w, bfhi(u0.y), acc[3]);
        acc[4] = fmaf(w, bflo(u0.z), acc[4]); acc[5] = fmaf(w, bfhi(u0.z), acc[5]);
        acc[6] = fmaf(w, bflo(u0.w), acc[6]); acc[7] = fmaf(w, bfhi(u0.w), acc[7]);
    }
    if (b < mcount) {
        int rem = mcount - b;
        int i0 = b + sub;
        int s0 = __shfl(srcReg, i0);
        float wx = __shfl(wReg.x, i0), wy = __shfl(wReg.y, i0);
        float wz = __shfl(wReg.z, i0), ww = __shfl(wReg.w, i0);
        if (sub < rem) {
            uint4 u0 = h1v4[(size_t)s0 * 16 + cg];
            float w = (hh < 2) ? ((hh == 0) ? wx : wy) : ((hh == 2) ? wz : ww);
            acc[0] = fmaf(w, bflo(u0.x), acc[0]); acc[1] = fmaf(w, bfhi(u0.x), acc[1]);
            acc[2] = fmaf(w, bflo(u0.y), acc[2]); acc[3] = fmaf(w, bfhi(u0.y), acc[3]);
            acc[4] = fmaf(w, bflo(u0.z), acc[4]); acc[5] = fmaf(w, bfhi(u0.z), acc[5]);
            acc[6] = fmaf(w, bflo(u0.w), acc[6]); acc[7] = fmaf(w, bfhi(u0.w), acc[7]);
        }
    }
}

__global__ void __launch_bounds__(256)
agg1_kernel(const int* __restrict__ csr, const int* __restrict__ indptr,
            const int* __restrict__ counts, const float* __restrict__ as1,
            const float* __restrict__ ad1, const unsigned short* __restrict__ h1b,
            const float* __restrict__ b1, float* __restrict__ x1, int N) {
    int lane = threadIdx.x & 63;
    int n = blockIdx.x * 4 + (threadIdx.x >> 6);
    if (n >= N) return;
    int start = indptr[n];
    int cnt = counts[n];
    float4 ad4 = ((const float4*)ad1)[n];

    int src0 = 0;
    float4 e0 = make_float4(-1e30f, -1e30f, -1e30f, -1e30f);
    if (lane < cnt) {
        src0 = csr[start + lane];
        float4 a = ((const float4*)as1)[src0];
        e0.x = leaky(a.x + ad4.x);
        e0.y = leaky(a.y + ad4.y);
        e0.z = leaky(a.z + ad4.z);
        e0.w = leaky(a.w + ad4.w);
    }
    float4 m4 = e0;
#pragma unroll
    for (int off = 32; off >= 1; off >>= 1) {
        m4.x = fmaxf(m4.x, __shfl_xor(m4.x, off));
        m4.y = fmaxf(m4.y, __shfl_xor(m4.y, off));
        m4.z = fmaxf(m4.z, __shfl_xor(m4.z, off));
        m4.w = fmaxf(m4.w, __shfl_xor(m4.w, off));
    }
    if (cnt > 64) {
        for (int base = 64; base < cnt; base += 64) {
            float4 e = make_float4(-1e30f, -1e30f, -1e30f, -1e30f);
            if (base + lane < cnt) {
                int s = csr[start + base + lane];
                float4 a = ((const float4*)as1)[s];
                e.x = leaky(a.x + ad4.x); e.y = leaky(a.y + ad4.y);
                e.z = leaky(a.z + ad4.z); e.w = leaky(a.w + ad4.w);
            }
#pragma unroll
            for (int off = 32; off >= 1; off >>= 1) {
                e.x = fmaxf(e.x, __shfl_xor(e.x, off));
                e.y = fmaxf(e.y, __shfl_xor(e.y, off));
                e.z = fmaxf(e.z, __shfl_xor(e.z, off));
                e.w = fmaxf(e.w, __shfl_xor(e.w, off));
            }
            m4.x = fmaxf(m4.x, e.x); m4.y = fmaxf(m4.y, e.y);
            m4.z = fmaxf(m4.z, e.z); m4.w = fmaxf(m4.w, e.w);
        }
    }
    float4 p0;
    p0.x = __expf(e0.x - m4.x);
    p0.y = __expf(e0.y - m4.y);
    p0.z = __expf(e0.z - m4.z);
    p0.w = __expf(e0.w - m4.w);
    float4 l4 = p0;
#pragma unroll
    for (int off = 32; off >= 1; off >>= 1) {
        l4.x += __shfl_xor(l4.x, off);
        l4.y += __shfl_xor(l4.y, off);
        l4.z += __shfl_xor(l4.z, off);
        l4.w += __shfl_xor(l4.w, off);
    }
    if (cnt > 64) {
        for (int base = 64; base < cnt; base += 64) {
            float4 p = make_float4(0.f, 0.f, 0.f, 0.f);
            if (base + lane < cnt) {
                int s = csr[start + base + lane];
                float4 a = ((const float4*)as1)[s];
                p.x = __expf(leaky(a.x + ad4.x) - m4.x);
                p.y = __expf(leaky(a.y + ad4.y) - m4.y);
                p.z = __expf(leaky(a.z + ad4.z) - m4.z);
                p.w = __expf(leaky(a.w + ad4.w) - m4.w);
            }
#pragma unroll
            for (int off = 32; off >= 1; off >>= 1) {
                p.x += __shfl_xor(p.x, off);
                p.y += __shfl_xor(p.y, off);
                p.z += __shfl_xor(p.z, off);
                p.w += __shfl_xor(p.w, off);
            }
            l4.x += p.x; l4.y += p.y; l4.z += p.z; l4.w += p.w;
        }
    }
    float4 li = make_float4(1.f / l4.x, 1.f / l4.y, 1.f / l4.z, 1.f / l4.w);
    float4 w0 = make_float4(p0.x * li.x, p0.y * li.y, p0.z * li.z, p0.w * li.w);

    int sub = lane >> 4;
    int cg = lane & 15;
    int hh = cg >> 2;
    const uint4* h1v4 = (const uint4*)h1b;
    float acc[8] = {0.f, 0.f, 0.f, 0.f, 0.f, 0.f, 0.f, 0.f};
    accum_group1(src0, w0, min(cnt, 64), h1v4, sub, cg, hh, acc);
    if (cnt > 64) {
        for (int base = 64; base < cnt; base += 64) {
            int srcc = 0;
            float4 wc = make_float4(0.f, 0.f, 0.f, 0.f);
            if (base + lane < cnt) {
                srcc = csr[start + base + lane];
                float4 a = ((const float4*)as1)[srcc];
                wc.x = __expf(leaky(a.x + ad4.x) - m4.x) * li.x;
                wc.y = __expf(leaky(a.y + ad4.y) - m4.y) * li.y;
                wc.z = __expf(leaky(a.z + ad4.z) - m4.z) * li.z;
                wc.w = __expf(leaky(a.w + ad4.w) - m4.w) * li.w;
            }
            accum_group1(srcc, wc, min(cnt - base, 64), h1v4, sub, cg, hh, acc);
        }
    }
#pragma unroll
    for (int i = 0; i < 8; i++) {
        acc[i] += __shfl_xor(acc[i], 16);
        acc[i] += __shfl_xor(acc[i], 32);
    }
    if (lane < 16) {
        float4 o0, o1;
        const float4* b4 = (const float4*)b1;
        float4 ba = b4[cg * 2], bb = b4[cg * 2 + 1];
        o0.x = acc[0] + ba.x; o0.y = acc[1] + ba.y; o0.z = acc[2] + ba.z; o0.w = acc[3] + ba.w;
        o1.x = acc[4] + bb.x; o1.y = acc[5] + bb.y; o1.z = acc[6] + bb.z; o1.w = acc[7] + bb.w;
        o0.x = (o0.x > 0.f) ? o0.x : (__expf(o0.x) - 1.f);
        o0.y = (o0.y > 0.f) ? o0.y : (__expf(o0.y) - 1.f);
        o0.z = (o0.z > 0.f) ? o0.z : (__expf(o0.z) - 1.f);
        o0.w = (o0.w > 0.f) ? o0.w : (__expf(o0.w) - 1.f);
        o1.x = (o1.x > 0.f) ? o1.x : (__expf(o1.x) - 1.f);
        o1.y = (o1.y > 0.f) ? o1.y : (__expf(o1.y) - 1.f);
        o1.z = (o1.z > 0.f) ? o1.z : (__expf(o1.z) - 1.f);
        o1.w = (o1.w > 0.f) ? o1.w : (__expf(o1.w) - 1.f);
        float4* xrow = (float4*)&x1[(size_t)n * 128 + cg * 8];
        xrow[0] = o0;
        xrow[1] = o1;
    }
}

// ---------------- aggregation layer 2: 8 edges per gather (bf16 rows) ----------------
// 8 lanes per edge (uint4 = 8 bf16 channels/lane), 8 edges per wave-load,
// 2 loads in flight per iter (16 edges). 3-stage shfl merge; lanes 0-7 write.

__device__ __forceinline__ void accum_group2(int srcReg, float wReg, int mcount,
                                             const uint4* __restrict__ h2v4,
                                             int sub, int cg, float* acc) {
    int b = 0;
    for (; b + 16 <= mcount; b += 16) {
        int i0 = b + sub, i1 = b + 8 + sub;
        int s0 = __shfl(srcReg, i0);
        int s1 = __shfl(srcReg, i1);
        float w_0 = __shfl(wReg, i0);
        float w_1 = __shfl(wReg, i1);
        uint4 u0 = h2v4[(size_t)s0 * 8 + cg];
        uint4 u1 = h2v4[(size_t)s1 * 8 + cg];
        acc[0] = fmaf(w_0, bflo(u0.x), acc[0]); acc[1] = fmaf(w_0, bfhi(u0.x), acc[1]);
        acc[2] = fmaf(w_0, bflo(u0.y), acc[2]); acc[3] = fmaf(w_0, bfhi(u0.y), acc[3]);
        acc[4] = fmaf(w_0, bflo(u0.z), acc[4]); acc[5] = fmaf(w_0, bfhi(u0.z), acc[5]);
        acc[6] = fmaf(w_0, bflo(u0.w), acc[6]); acc[7] = fmaf(w_0, bfhi(u0.w), acc[7]);
        acc[0] = fmaf(w_1, bflo(u1.x), acc[0]); acc[1] = fmaf(w_1, bfhi(u1.x), acc[1]);
        acc[2] = fmaf(w_1, bflo(u1.y), acc[2]); acc[3] = fmaf(w_1, bfhi(u1.y), acc[3]);
        acc[4] = fmaf(w_1, bflo(u1.z), acc[4]); acc[5] = fmaf(w_1, bfhi(u1.z), acc[5]);
        acc[6] = fmaf(w_1, bflo(u1.w), acc[6]); acc[7] = fmaf(w_1, bfhi(u1.w), acc[7]);
    }
    for (; b + 8 <= mcount; b += 8) {
        int i0 = b + sub;
        int s0 = __shfl(srcReg, i0);
        float w_0 = __shfl(wReg, i0);
        uint4 u0 = h2v4[(size_t)s0 * 8 + cg];
        acc[0] = fmaf(w_0, bflo(u0.x), acc[0]); acc[1] = fmaf(w_0, bfhi(u0.x), acc[1]);
        acc[2] = fmaf(w_0, bflo(u0.y), acc[2]); acc[3] = fmaf(w_0, bfhi(u0.y), acc[3]);
        acc[4] = fmaf(w_0, bflo(u0.z), acc[4]); acc[5] = fmaf(w_0, bfhi(u0.z), acc[5]);
        acc[6] = fmaf(w_0, bflo(u0.w), acc[6]); acc[7] = fmaf(w_0, bfhi(u0.w), acc[7]);
    }
    if (b < mcount) {
        int rem = mcount - b;
        int i0 = b + sub;
        int s0 = __shfl(srcReg, i0);
        float w_0 = __shfl(wReg, i0);
        if (sub < rem) {
            uint4 u0 = h2v4[(size_t)s0 * 8 + cg];
            acc[0] = fmaf(w_0, bflo(u0.x), acc[0]); acc[1] = fmaf(w_0, bfhi(u0.x), acc[1]);
            acc[2] = fmaf(w_0, bflo(u0.y), acc[2]); acc[3] = fmaf(w_0, bfhi(u0.y), acc[3]);
            acc[4] = fmaf(w_0, bflo(u0.z), acc[4]); acc[5] = fmaf(w_0, bfhi(u0.z), acc[5]);
            acc[6] = fmaf(w_0, bflo(u0.w), acc[6]); acc[7] = fmaf(w_0, bfhi(u0.w), acc[7]);
        }
    }
}

__global__ void __launch_bounds__(256)
agg2_kernel(const int* __restrict__ csr, const int* __restrict__ indptr,
            const int* __restrict__ counts, const float* __restrict__ as2,
            const float* __restrict__ ad2, const unsigned short* __restrict__ h2b,
            const float* __restrict__ b2, float* __restrict__ out, int N) {
    int lane = threadIdx.x & 63;
    int n = blockIdx.x * 4 + (threadIdx.x >> 6);
    if (n >= N) return;
    int start = indptr[n];
    int cnt = counts[n];
    float ad = ad2[n];

    int src0 = 0;
    float e0 = -1e30f;
    if (lane < cnt) {
        src0 = csr[start + lane];
        e0 = leaky(as2[src0] + ad);
    }
    float m = e0;
#pragma unroll
    for (int off = 32; off >= 1; off >>= 1) m = fmaxf(m, __shfl_xor(m, off));
    if (cnt > 64) {
        for (int base = 64; base < cnt; base += 64) {
            float e = -1e30f;
            if (base + lane < cnt) e = leaky(as2[csr[start + base + lane]] + ad);
#pragma unroll
            for (int off = 32; off >= 1; off >>= 1) e = fmaxf(e, __shfl_xor(e, off));
            m = fmaxf(m, e);
        }
    }
    float p0 = __expf(e0 - m);
    float l = p0;
#pragma unroll
    for (int off = 32; off >= 1; off >>= 1) l += __shfl_xor(l, off);
    if (cnt > 64) {
        for (int base = 64; base < cnt; base += 64) {
            float p = 0.f;
            if (base + lane < cnt) p = __expf(leaky(as2[csr[start + base + lane]] + ad) - m);
#pragma unroll
            for (int off = 32; off >= 1; off >>= 1) p += __shfl_xor(p, off);
            l += p;
        }
    }
    float li = 1.f / l;
    float w0 = p0 * li;

    int sub = lane >> 3;   // edge within 8-group
    int cg = lane & 7;     // channel group (8 ch each)
    const uint4* h2v4 = (const uint4*)h2b;
    float acc[8] = {0.f, 0.f, 0.f, 0.f, 0.f, 0.f, 0.f, 0.f};
    accum_group2(src0, w0, min(cnt, 64), h2v4, sub, cg, acc);
    if (cnt > 64) {
        for (int base = 64; base < cnt; base += 64) {
            int srcc = 0;
            float wc = 0.f;
            if (base + lane < cnt) {
                srcc = csr[start + base + lane];
                wc = __expf(leaky(as2[srcc] + ad) - m) * li;
            }
            accum_group2(srcc, wc, min(cnt - base, 64), h2v4, sub, cg, acc);
        }
    }
#pragma unroll
    for (int i = 0; i < 8; i++) {
        acc[i] += __shfl_xor(acc[i], 8);
        acc[i] += __shfl_xor(acc[i], 16);
        acc[i] += __shfl_xor(acc[i], 32);
    }
    if (lane < 8) {
        const float4* b4 = (const float4*)b2;
        float4 ba = b4[cg * 2], bb = b4[cg * 2 + 1];
        float4 o0, o1;
        o0.x = acc[0] + ba.x; o0.y = acc[1] + ba.y; o0.z = acc[2] + ba.z; o0.w = acc[3] + ba.w;
        o1.x = acc[4] + bb.x; o1.y = acc[5] + bb.y; o1.z = acc[6] + bb.z; o1.w = acc[7] + bb.w;
        float4* orow = (float4*)&out[(size_t)n * 64 + cg * 8];
        orow[0] = o0;
        orow[1] = o1;
    }
}

// ---------------- launcher ----------------

extern "C" void kernel_launch(void* const* d_in, const int* in_sizes, int n_in,
                              void* d_out, int out_size, void* d_ws, size_t ws_size,
                              hipStream_t stream) {
    const int*   xidx = (const int*)d_in[0];
    const int*   ei   = (const int*)d_in[1];
    const float* emb  = (const float*)d_in[2];
    const float* W1   = (const float*)d_in[3];
    const float* a_s1 = (const float*)d_in[4];
    const float* a_d1 = (const float*)d_in[5];
    const float* b1   = (const float*)d_in[6];
    const float* W2   = (const float*)d_in[7];
    const float* a_s2 = (const float*)d_in[8];
    const float* a_d2 = (const float*)d_in[9];
    const float* b2   = (const float*)d_in[10];
    float* out = (float*)d_out;

    const int N  = in_sizes[0];
    const int E  = in_sizes[1] / 2;
    const int E2 = E + N;
    const int K  = (N + 255) >> BK_SHIFT;   // 391 buckets for N=100000

    // workspace layout
    int* ws_i    = (int*)d_ws;
    int* counts  = ws_i;                       // N
    int* indptr  = ws_i + N;                   // N
    int* bcounts = ws_i + 2 * (size_t)N;       // 512
    int* bbase   = ws_i + 2 * (size_t)N + 512; // 513
    int* bcursor = ws_i + 2 * (size_t)N + 1032;// 512
    int* csr     = ws_i + 2 * (size_t)N + 1544;// E2
    size_t fbase = ((size_t)(2 * (size_t)N + 1544 + E2) + 3) & ~(size_t)3;
    float* ws_f = (float*)d_ws;
    unsigned short* h1b = (unsigned short*)(ws_f + fbase);   // N*128 bf16
    float* x1  = ws_f + fbase + (size_t)N * 64;              // N*128 floats
    float* as1 = x1 + (size_t)N * 128;                       // N*4
    float* ad1 = as1 + (size_t)N * 4;                        // N*4
    unsigned short* h2b = h1b;    // alias: h1b dead after agg1 (h2b = N*64 bf16)
    float* as2 = as1;             // alias
    float* ad2 = ad1;
    uint2* bedges = (uint2*)x1;   // alias: bedges dead before agg1 writes x1

    // CSR build: dst-radix partition
    int nchunks = (E2 + 4095) / 4096;
    zero_kernel<<<(K + 255) / 256, 256, 0, stream>>>(bcounts, K);
    bcount_kernel<<<nchunks, 256, 0, stream>>>(ei, E, E2, K, bcounts);
    bscan_kernel<<<1, 512, 0, stream>>>(bcounts, K, bbase, bcursor);
    bscatter_kernel<<<nchunks, 256, 0, stream>>>(ei, E, E2, K, bcursor, bedges);
    bcsr_kernel<<<K, 256, 0, stream>>>(bedges, bbase, N, counts, indptr, csr);

    // Layer 1 (gemm1 fuses alpha1 + bf16 h1)
    {
        dim3 g((N + 63) / 64, 2);
        gemm1_kernel<<<g, 256, 0, stream>>>(emb, xidx, W1, h1b, a_s1, a_d1, as1, ad1, N);
    }
    agg1_kernel<<<(N + 3) / 4, 256, 0, stream>>>(csr, indptr, counts, as1, ad1, h1b, b1, x1, N);

    // Layer 2 (gemm2 fuses alpha2 + bf16 h2)
    gemm2_kernel<<<(N + 63) / 64, 256, 0, stream>>>(x1, W2, h2b, a_s2, a_d2, as2, ad2, N);
    agg2_kernel<<<(N + 3) / 4, 256, 0, stream>>>(csr, indptr, counts, as2, ad2, h2b, b2, out, N);
}

// Round 9
// 443.038 us; speedup vs baseline: 1.4693x; 1.0018x over previous
//
#include <hip/hip_runtime.h>
#include <math.h>

// GATNet: N=100000 nodes, D=128, HEADS=4, HID=32, OUT_C=64, E=1.6M (+N self-loops)
#define NEG_SLOPE 0.2f
#define BK_SHIFT 8          // bucket = dst >> 8 (256 dsts per bucket)

typedef __attribute__((ext_vector_type(2))) float v2f;

__device__ __forceinline__ float leaky(float x) { return x > 0.f ? x : NEG_SLOPE * x; }
__device__ __forceinline__ float dot4(float4 a, float4 b) {
    return a.x * b.x + a.y * b.y + a.z * b.z + a.w * b.w;
}
// fp32 -> bf16 round-to-nearest-even
__device__ __forceinline__ unsigned short f2bf(float f) {
    unsigned int x = __float_as_uint(f);
    unsigned int r = (x + 0x7fffu + ((x >> 16) & 1u)) >> 16;
    return (unsigned short)r;
}
__device__ __forceinline__ float bflo(unsigned int u) { return __uint_as_float(u << 16); }
__device__ __forceinline__ float bfhi(unsigned int u) { return __uint_as_float(u & 0xffff0000u); }

// ---------------- CSR build: dst-radix partition ----------------

__global__ void zero_kernel(int* __restrict__ p, int n) {
    int i = blockIdx.x * blockDim.x + threadIdx.x;
    if (i < n) p[i] = 0;
}

__global__ void __launch_bounds__(256) bcount_kernel(const int* __restrict__ ei, int E, int E2,
                                                     int K, int* __restrict__ bcounts) {
    __shared__ int h[512];
    int t = threadIdx.x;
    h[t] = 0; h[t + 256] = 0;
    __syncthreads();
    int base = blockIdx.x * 4096;
#pragma unroll 4
    for (int i = 0; i < 16; i++) {
        int e = base + i * 256 + t;
        if (e < E2) {
            int dst = (e < E) ? ei[E + e] : (e - E);
            atomicAdd(&h[dst >> BK_SHIFT], 1);
        }
    }
    __syncthreads();
    for (int b = t; b < K; b += 256) {
        int c = h[b];
        if (c) atomicAdd(&bcounts[b], c);
    }
}

__global__ void __launch_bounds__(512) bscan_kernel(const int* __restrict__ bcounts, int K,
                                                    int* __restrict__ bbase, int* __restrict__ bcursor) {
    __shared__ int s[512];
    int t = threadIdx.x;
    int v = (t < K) ? bcounts[t] : 0;
    s[t] = v;
    __syncthreads();
    for (int off = 1; off < 512; off <<= 1) {
        int u = (t >= off) ? s[t - off] : 0;
        __syncthreads();
        s[t] += u;
        __syncthreads();
    }
    if (t < K) {
        int ex = s[t] - v;
        bbase[t] = ex;
        bcursor[t] = ex;
    }
    if (t == 511) bbase[K] = s[511];
}

// stage packed (src<<8 | dstLow8) + u16 bin tag; copy out in coalesced runs
__global__ void __launch_bounds__(256) bscatter_kernel(const int* __restrict__ ei, int E, int E2,
                                                       int K, int* __restrict__ bcursor,
                                                       unsigned int* __restrict__ bedges) {
    __shared__ int hist[512], pre[512], lcur[512], gbase[512], psum[256];
    __shared__ unsigned int stage[4096];
    __shared__ unsigned short binof[4096];
    int t = threadIdx.x;
    hist[t] = 0; hist[t + 256] = 0;
    __syncthreads();
    int base = blockIdx.x * 4096;
    int cnt = min(4096, E2 - base);
    int s_[16], d_[16];
#pragma unroll
    for (int i = 0; i < 16; i++) {
        int e = base + i * 256 + t;
        if (e < E2) {
            int ss, dd;
            if (e < E) { ss = ei[e]; dd = ei[E + e]; }
            else       { ss = e - E; dd = ss; }
            s_[i] = ss; d_[i] = dd;
            atomicAdd(&hist[dd >> BK_SHIFT], 1);
        }
    }
    __syncthreads();
    int a0 = hist[2 * t], a1 = hist[2 * t + 1];
    psum[t] = a0 + a1;
    __syncthreads();
    for (int off = 1; off < 256; off <<= 1) {
        int u = (t >= off) ? psum[t - off] : 0;
        __syncthreads();
        psum[t] += u;
        __syncthreads();
    }
    int pex = psum[t] - (a0 + a1);
    pre[2 * t] = pex;
    pre[2 * t + 1] = pex + a0;
    __syncthreads();
    for (int b = t; b < K; b += 256) {
        int c = hist[b];
        if (c) gbase[b] = atomicAdd(&bcursor[b], c);
    }
    lcur[t] = pre[t]; lcur[t + 256] = pre[t + 256];
    __syncthreads();
#pragma unroll
    for (int i = 0; i < 16; i++) {
        int e = base + i * 256 + t;
        if (e < E2) {
            int bin = d_[i] >> BK_SHIFT;
            int p = atomicAdd(&lcur[bin], 1);
            stage[p] = ((unsigned)s_[i] << 8) | (unsigned)(d_[i] & 255);
            binof[p] = (unsigned short)bin;
        }
    }
    __syncthreads();
    for (int i = t; i < cnt; i += 256) {
        unsigned int ed = stage[i];
        int bin = (int)binof[i];
        bedges[gbase[bin] + (i - pre[bin])] = ed;
    }
}

__global__ void __launch_bounds__(256) bcsr_kernel(const unsigned int* __restrict__ bedges,
                                                   const int* __restrict__ bbase, int N,
                                                   int* __restrict__ counts, int* __restrict__ indptr,
                                                   int* __restrict__ csr) {
    __shared__ int hist[256], scn[256], cur[256];
    int b = blockIdx.x;
    int t = threadIdx.x;
    int base = bbase[b];
    int cnt = bbase[b + 1] - base;
    hist[t] = 0;
    __syncthreads();
    for (int i = t; i < cnt; i += 256) {
        atomicAdd(&hist[bedges[base + i] & 255u], 1);
    }
    __syncthreads();
    int v = hist[t];
    scn[t] = v;
    __syncthreads();
    for (int off = 1; off < 256; off <<= 1) {
        int u = (t >= off) ? scn[t - off] : 0;
        __syncthreads();
        scn[t] += u;
        __syncthreads();
    }
    int ex = scn[t] - v;
    int d = (b << BK_SHIFT) + t;
    if (d < N) { counts[d] = v; indptr[d] = base + ex; }
    cur[t] = ex;
    __syncthreads();
    for (int i = t; i < cnt; i += 256) {
        unsigned int ed = bedges[base + i];
        int p = atomicAdd(&cur[ed & 255u], 1);
        csr[base + p] = (int)(ed >> 8);
    }
}

// ---------------- gemm1 + fused alpha1, bf16 h1 output ----------------

__global__ __launch_bounds__(256) void gemm1_kernel(const float* __restrict__ emb,
                             const int* __restrict__ xidx,
                             const float* __restrict__ W1,
                             unsigned short* __restrict__ h1b,
                             const float* __restrict__ a_s1, const float* __restrict__ a_d1,
                             float* __restrict__ as1, float* __restrict__ ad1, int N) {
    __shared__ float xs[64][128];
    __shared__ float ws[128][64];
    int tid = threadIdx.x;
    int r0 = blockIdx.x * 64;
    int c0 = blockIdx.y * 64;
    {
        const float4* W4 = (const float4*)W1;
        float4* ws4 = (float4*)ws;
        int cbase = c0 >> 2;
        for (int i = tid; i < 128 * 16; i += 256) {
            int k = i >> 4, c = i & 15;
            ws4[i] = W4[k * 32 + cbase + c];
        }
    }
    {
        float4* xs4 = (float4*)xs;
        for (int i = tid; i < 64 * 32; i += 256) {
            int r = i >> 5, c = i & 31;
            int row = r0 + r;
            float4 v = make_float4(0.f, 0.f, 0.f, 0.f);
            if (row < N) {
                int s = xidx[row];
                v = ((const float4*)emb)[(size_t)s * 32 + c];
            }
            xs4[i] = v;
        }
    }
    __syncthreads();
    int tr = tid >> 4;
    int tc = tid & 15;
    float4 acc[4];
    acc[0] = acc[1] = acc[2] = acc[3] = make_float4(0.f, 0.f, 0.f, 0.f);
    for (int k = 0; k < 128; k += 4) {
        float4 wv0 = *(const float4*)&ws[k][tc * 4];
        float4 wv1 = *(const float4*)&ws[k + 1][tc * 4];
        float4 wv2 = *(const float4*)&ws[k + 2][tc * 4];
        float4 wv3 = *(const float4*)&ws[k + 3][tc * 4];
#pragma unroll
        for (int i = 0; i < 4; i++) {
            float4 xv = *(const float4*)&xs[tr * 4 + i][k];
            acc[i].x = fmaf(xv.x, wv0.x, acc[i].x);
            acc[i].y = fmaf(xv.x, wv0.y, acc[i].y);
            acc[i].z = fmaf(xv.x, wv0.z, acc[i].z);
            acc[i].w = fmaf(xv.x, wv0.w, acc[i].w);
            acc[i].x = fmaf(xv.y, wv1.x, acc[i].x);
            acc[i].y = fmaf(xv.y, wv1.y, acc[i].y);
            acc[i].z = fmaf(xv.y, wv1.z, acc[i].z);
            acc[i].w = fmaf(xv.y, wv1.w, acc[i].w);
            acc[i].x = fmaf(xv.z, wv2.x, acc[i].x);
            acc[i].y = fmaf(xv.z, wv2.y, acc[i].y);
            acc[i].z = fmaf(xv.z, wv2.z, acc[i].z);
            acc[i].w = fmaf(xv.z, wv2.w, acc[i].w);
            acc[i].x = fmaf(xv.w, wv3.x, acc[i].x);
            acc[i].y = fmaf(xv.w, wv3.y, acc[i].y);
            acc[i].z = fmaf(xv.w, wv3.z, acc[i].z);
            acc[i].w = fmaf(xv.w, wv3.w, acc[i].w);
        }
    }
    int colbase = c0 + tc * 4;
    int h = colbase >> 5;
    int off = colbase & 31;
    float4 av = *(const float4*)&a_s1[h * 32 + off];
    float4 dv = *(const float4*)&a_d1[h * 32 + off];
#pragma unroll
    for (int i = 0; i < 4; i++) {
        int row = r0 + tr * 4 + i;
        if (row < N) {
            ushort4 pk;
            pk.x = f2bf(acc[i].x); pk.y = f2bf(acc[i].y);
            pk.z = f2bf(acc[i].z); pk.w = f2bf(acc[i].w);
            *(ushort4*)&h1b[(size_t)row * 128 + colbase] = pk;
        }
        float ps = dot4(acc[i], av);
        float pd = dot4(acc[i], dv);
        ps += __shfl_xor(ps, 1); pd += __shfl_xor(pd, 1);
        ps += __shfl_xor(ps, 2); pd += __shfl_xor(pd, 2);
        ps += __shfl_xor(ps, 4); pd += __shfl_xor(pd, 4);
        if ((tc & 7) == 0 && row < N) {
            as1[row * 4 + h] = ps;
            ad1[row * 4 + h] = pd;
        }
    }
}

// ---------------- gemm2 + fused alpha2, bf16 x1 input, bf16 h2 output ----------------

__global__ __launch_bounds__(256) void gemm2_kernel(const unsigned short* __restrict__ x1b,
                             const float* __restrict__ W2,
                             unsigned short* __restrict__ h2b,
                             const float* __restrict__ a_s2, const float* __restrict__ a_d2,
                             float* __restrict__ as2, float* __restrict__ ad2, int N) {
    __shared__ float xs[64][128];
    __shared__ float ws[128][64];
    int tid = threadIdx.x;
    int r0 = blockIdx.x * 64;
    {
        const float4* W4 = (const float4*)W2;
        float4* ws4 = (float4*)ws;
        for (int i = tid; i < 128 * 16; i += 256) ws4[i] = W4[i];
    }
    {   // stage bf16 x1 -> fp32 LDS
        const uint4* x4 = (const uint4*)x1b;   // 8 bf16 per uint4; row = 16 uint4
        for (int i = tid; i < 64 * 16; i += 256) {
            int r = i >> 4, c = i & 15;
            int row = r0 + r;
            uint4 u = make_uint4(0u, 0u, 0u, 0u);
            if (row < N) u = x4[(size_t)row * 16 + c];
            float* dst = &xs[r][c * 8];
            dst[0] = bflo(u.x); dst[1] = bfhi(u.x);
            dst[2] = bflo(u.y); dst[3] = bfhi(u.y);
            dst[4] = bflo(u.z); dst[5] = bfhi(u.z);
            dst[6] = bflo(u.w); dst[7] = bfhi(u.w);
        }
    }
    __syncthreads();
    int tr = tid >> 4;
    int tc = tid & 15;
    float4 acc[4];
    acc[0] = acc[1] = acc[2] = acc[3] = make_float4(0.f, 0.f, 0.f, 0.f);
    for (int k = 0; k < 128; k += 4) {
        float4 wv0 = *(const float4*)&ws[k][tc * 4];
        float4 wv1 = *(const float4*)&ws[k + 1][tc * 4];
        float4 wv2 = *(const float4*)&ws[k + 2][tc * 4];
        float4 wv3 = *(const float4*)&ws[k + 3][tc * 4];
#pragma unroll
        for (int i = 0; i < 4; i++) {
            float4 xv = *(const float4*)&xs[tr * 4 + i][k];
            acc[i].x = fmaf(xv.x, wv0.x, acc[i].x);
            acc[i].y = fmaf(xv.x, wv0.y, acc[i].y);
            acc[i].z = fmaf(xv.x, wv0.z, acc[i].z);
            acc[i].w = fmaf(xv.x, wv0.w, acc[i].w);
            acc[i].x = fmaf(xv.y, wv1.x, acc[i].x);
            acc[i].y = fmaf(xv.y, wv1.y, acc[i].y);
            acc[i].z = fmaf(xv.y, wv1.z, acc[i].z);
            acc[i].w = fmaf(xv.y, wv1.w, acc[i].w);
            acc[i].x = fmaf(xv.z, wv2.x, acc[i].x);
            acc[i].y = fmaf(xv.z, wv2.y, acc[i].y);
            acc[i].z = fmaf(xv.z, wv2.z, acc[i].z);
            acc[i].w = fmaf(xv.z, wv2.w, acc[i].w);
            acc[i].x = fmaf(xv.w, wv3.x, acc[i].x);
            acc[i].y = fmaf(xv.w, wv3.y, acc[i].y);
            acc[i].z = fmaf(xv.w, wv3.z, acc[i].z);
            acc[i].w = fmaf(xv.w, wv3.w, acc[i].w);
        }
    }
    float4 av = *(const float4*)&a_s2[tc * 4];
    float4 dv = *(const float4*)&a_d2[tc * 4];
#pragma unroll
    for (int i = 0; i < 4; i++) {
        int row = r0 + tr * 4 + i;
        if (row < N) {
            ushort4 pk;
            pk.x = f2bf(acc[i].x); pk.y = f2bf(acc[i].y);
            pk.z = f2bf(acc[i].z); pk.w = f2bf(acc[i].w);
            *(ushort4*)&h2b[(size_t)row * 64 + tc * 4] = pk;
        }
        float ps = dot4(acc[i], av);
        float pd = dot4(acc[i], dv);
        ps += __shfl_xor(ps, 1); pd += __shfl_xor(pd, 1);
        ps += __shfl_xor(ps, 2); pd += __shfl_xor(pd, 2);
        ps += __shfl_xor(ps, 4); pd += __shfl_xor(pd, 4);
        ps += __shfl_xor(ps, 8); pd += __shfl_xor(pd, 8);
        if (tc == 0 && row < N) { as2[row] = ps; ad2[row] = pd; }
    }
}

// ---------------- aggregation layer 1 ----------------
// Wave per node; 4 edges per wave-load (16 lanes/edge, uint4 = 8 bf16 ch/lane).
// Weights in an LDS table (1 ds_read replaces 4 shfl + 3 select); packed-pair
// (v_pk_fma_f32) accumulate; x1 written bf16.

__device__ __forceinline__ void accum_tbl1(int srcReg, const float* __restrict__ ew, int mcount,
                                           const uint4* __restrict__ h1v4,
                                           int sub, int cg, int hh, v2f* acc) {
    int b = 0;
    for (; b + 8 <= mcount; b += 8) {
        int i0 = b + sub, i1 = b + 4 + sub;
        int s0 = __shfl(srcReg, i0);
        int s1 = __shfl(srcReg, i1);
        float w_0 = ew[i0 * 4 + hh];
        float w_1 = ew[i1 * 4 + hh];
        uint4 u0 = h1v4[(size_t)s0 * 16 + cg];
        uint4 u1 = h1v4[(size_t)s1 * 16 + cg];
        v2f wv0 = {w_0, w_0}, wv1 = {w_1, w_1};
        v2f t;
        t.x = bflo(u0.x); t.y = bfhi(u0.x); acc[0] += wv0 * t;
        t.x = bflo(u0.y); t.y = bfhi(u0.y); acc[1] += wv0 * t;
        t.x = bflo(u0.z); t.y = bfhi(u0.z); acc[2] += wv0 * t;
        t.x = bflo(u0.w); t.y = bfhi(u0.w); acc[3] += wv0 * t;
        t.x = bflo(u1.x); t.y = bfhi(u1.x); acc[0] += wv1 * t;
        t.x = bflo(u1.y); t.y = bfhi(u1.y); acc[1] += wv1 * t;
        t.x = bflo(u1.z); t.y = bfhi(u1.z); acc[2] += wv1 * t;
        t.x = bflo(u1.w); t.y = bfhi(u1.w); acc[3] += wv1 * t;
    }
    for (; b + 4 <= mcount; b += 4) {
        int i0 = b + sub;
        int s0 = __shfl(srcReg, i0);
        float w_0 = ew[i0 * 4 + hh];
        uint4 u0 = h1v4[(size_t)s0 * 16 + cg];
        v2f wv0 = {w_0, w_0};
        v2f t;
        t.x = bflo(u0.x); t.y = bfhi(u0.x); acc[0] += wv0 * t;
        t.x = bflo(u0.y); t.y = bfhi(u0.y); acc[1] += wv0 * t;
        t.x = bflo(u0.z); t.y = bfhi(u0.z); acc[2] += wv0 * t;
        t.x = bflo(u0.w); t.y = bfhi(u0.w); acc[3] += wv0 * t;
    }
    if (b < mcount) {
        int rem = mcount - b;
        int i0 = b + sub;
        int ic = min(i0, mcount - 1);
        int s0 = __shfl(srcReg, ic);        // all lanes active at the shfl
        if (sub < rem) {
            float w_0 = ew[i0 * 4 + hh];    // i0 < mcount <= 64 here
            uint4 u0 = h1v4[(size_t)s0 * 16 + cg];
            v2f wv0 = {w_0, w_0};
            v2f t;
            t.x = bflo(u0.x); t.y = bfhi(u0.x); acc[0] += wv0 * t;
            t.x = bflo(u0.y); t.y = bfhi(u0.y); acc[1] += wv0 * t;
            t.x = bflo(u0.z); t.y = bfhi(u0.z); acc[2] += wv0 * t;
            t.x = bflo(u0.w); t.y = bfhi(u0.w); acc[3] += wv0 * t;
        }
    }
}

__global__ void __launch_bounds__(256)
agg1_kernel(const int* __restrict__ csr, const int* __restrict__ indptr,
            const int* __restrict__ counts, const float* __restrict__ as1,
            const float* __restrict__ ad1, const unsigned short* __restrict__ h1b,
            const float* __restrict__ b1, unsigned short* __restrict__ x1b, int N) {
    __shared__ float ewt[4][256];
    int lane = threadIdx.x & 63;
    int wv = threadIdx.x >> 6;
    int n = blockIdx.x * 4 + wv;
    if (n >= N) return;
    int start = indptr[n];
    int cnt = counts[n];
    float4 ad4 = ((const float4*)ad1)[n];

    // Phase A: lane i <-> edge i (first 64 edges)
    int src0 = 0;
    float4 e0 = make_float4(-1e30f, -1e30f, -1e30f, -1e30f);
    if (lane < cnt) {
        src0 = csr[start + lane];
        float4 a = ((const float4*)as1)[src0];
        e0.x = leaky(a.x + ad4.x);
        e0.y = leaky(a.y + ad4.y);
        e0.z = leaky(a.z + ad4.z);
        e0.w = leaky(a.w + ad4.w);
    }
    float4 m4 = e0;
#pragma unroll
    for (int off = 32; off >= 1; off >>= 1) {
        m4.x = fmaxf(m4.x, __shfl_xor(m4.x, off));
        m4.y = fmaxf(m4.y, __shfl_xor(m4.y, off));
        m4.z = fmaxf(m4.z, __shfl_xor(m4.z, off));
        m4.w = fmaxf(m4.w, __shfl_xor(m4.w, off));
    }
    if (cnt > 64) {
        for (int base = 64; base < cnt; base += 64) {
            float4 e = make_float4(-1e30f, -1e30f, -1e30f, -1e30f);
            if (base + lane < cnt) {
                int s = csr[start + base + lane];
                float4 a = ((const float4*)as1)[s];
                e.x = leaky(a.x + ad4.x); e.y = leaky(a.y + ad4.y);
                e.z = leaky(a.z + ad4.z); e.w = leaky(a.w + ad4.w);
            }
#pragma unroll
            for (int off = 32; off >= 1; off >>= 1) {
                e.x = fmaxf(e.x, __shfl_xor(e.x, off));
                e.y = fmaxf(e.y, __shfl_xor(e.y, off));
                e.z = fmaxf(e.z, __shfl_xor(e.z, off));
                e.w = fmaxf(e.w, __shfl_xor(e.w, off));
            }
            m4.x = fmaxf(m4.x, e.x); m4.y = fmaxf(m4.y, e.y);
            m4.z = fmaxf(m4.z, e.z); m4.w = fmaxf(m4.w, e.w);
        }
    }
    float4 p0;
    p0.x = __expf(e0.x - m4.x);
    p0.y = __expf(e0.y - m4.y);
    p0.z = __expf(e0.z - m4.z);
    p0.w = __expf(e0.w - m4.w);
    float4 l4 = p0;
#pragma unroll
    for (int off = 32; off >= 1; off >>= 1) {
        l4.x += __shfl_xor(l4.x, off);
        l4.y += __shfl_xor(l4.y, off);
        l4.z += __shfl_xor(l4.z, off);
        l4.w += __shfl_xor(l4.w, off);
    }
    if (cnt > 64) {
        for (int base = 64; base < cnt; base += 64) {
            float4 p = make_float4(0.f, 0.f, 0.f, 0.f);
            if (base + lane < cnt) {
                int s = csr[start + base + lane];
                float4 a = ((const float4*)as1)[s];
                p.x = __expf(leaky(a.x + ad4.x) - m4.x);
                p.y = __expf(leaky(a.y + ad4.y) - m4.y);
                p.z = __expf(leaky(a.z + ad4.z) - m4.z);
                p.w = __expf(leaky(a.w + ad4.w) - m4.w);
            }
#pragma unroll
            for (int off = 32; off >= 1; off >>= 1) {
                p.x += __shfl_xor(p.x, off);
                p.y += __shfl_xor(p.y, off);
                p.z += __shfl_xor(p.z, off);
                p.w += __shfl_xor(p.w, off);
            }
            l4.x += p.x; l4.y += p.y; l4.z += p.z; l4.w += p.w;
        }
    }
    float4 li = make_float4(1.f / l4.x, 1.f / l4.y, 1.f / l4.z, 1.f / l4.w);
    float4 w0 = make_float4(p0.x * li.x, p0.y * li.y, p0.z * li.z, p0.w * li.w);

    // weight table to LDS (same-wave write/read: no barrier needed)
    float* ew = ewt[wv];
    *(float4*)&ew[lane * 4] = w0;

    int sub = lane >> 4;
    int cg = lane & 15;
    int hh = cg >> 2;
    const uint4* h1v4 = (const uint4*)h1b;
    v2f acc[4];
    acc[0] = acc[1] = acc[2] = acc[3] = (v2f){0.f, 0.f};
    accum_tbl1(src0, ew, min(cnt, 64), h1v4, sub, cg, hh, acc);
    if (cnt > 64) {
        for (int base = 64; base < cnt; base += 64) {
            int srcc = 0;
            float4 wc = make_float4(0.f, 0.f, 0.f, 0.f);
            if (base + lane < cnt) {
                srcc = csr[start + base + lane];
                float4 a = ((const float4*)as1)[srcc];
                wc.x = __expf(leaky(a.x + ad4.x) - m4.x) * li.x;
                wc.y = __expf(leaky(a.y + ad4.y) - m4.y) * li.y;
                wc.z = __expf(leaky(a.z + ad4.z) - m4.z) * li.z;
                wc.w = __expf(leaky(a.w + ad4.w) - m4.w) * li.w;
            }
            *(float4*)&ew[lane * 4] = wc;   // overwrite table (intra-wave ordered)
            accum_tbl1(srcc, ew, min(cnt - base, 64), h1v4, sub, cg, hh, acc);
        }
    }
    // merge the 4 sub-group partials
#pragma unroll
    for (int i = 0; i < 4; i++) {
        acc[i].x += __shfl_xor(acc[i].x, 16);
        acc[i].x += __shfl_xor(acc[i].x, 32);
        acc[i].y += __shfl_xor(acc[i].y, 16);
        acc[i].y += __shfl_xor(acc[i].y, 32);
    }
    if (lane < 16) {
        const float4* b4 = (const float4*)b1;
        float4 ba = b4[cg * 2], bb = b4[cg * 2 + 1];
        float o[8];
        o[0] = acc[0].x + ba.x; o[1] = acc[0].y + ba.y;
        o[2] = acc[1].x + ba.z; o[3] = acc[1].y + ba.w;
        o[4] = acc[2].x + bb.x; o[5] = acc[2].y + bb.y;
        o[6] = acc[3].x + bb.z; o[7] = acc[3].y + bb.w;
#pragma unroll
        for (int j = 0; j < 8; j++) o[j] = (o[j] > 0.f) ? o[j] : (__expf(o[j]) - 1.f);  // ELU
        uint4 pk;
        pk.x = (unsigned)f2bf(o[0]) | ((unsigned)f2bf(o[1]) << 16);
        pk.y = (unsigned)f2bf(o[2]) | ((unsigned)f2bf(o[3]) << 16);
        pk.z = (unsigned)f2bf(o[4]) | ((unsigned)f2bf(o[5]) << 16);
        pk.w = (unsigned)f2bf(o[6]) | ((unsigned)f2bf(o[7]) << 16);
        *(uint4*)&x1b[(size_t)n * 128 + cg * 8] = pk;
    }
}

// ---------------- aggregation layer 2: 8 edges per gather (bf16 rows) ----------------

__device__ __forceinline__ void accum2(int srcReg, float wReg, int mcount,
                                       const uint4* __restrict__ h2v4,
                                       int sub, int cg, v2f* acc) {
    int b = 0;
    for (; b + 16 <= mcount; b += 16) {
        int i0 = b + sub, i1 = b + 8 + sub;
        int s0 = __shfl(srcReg, i0);
        int s1 = __shfl(srcReg, i1);
        float w_0 = __shfl(wReg, i0);
        float w_1 = __shfl(wReg, i1);
        uint4 u0 = h2v4[(size_t)s0 * 8 + cg];
        uint4 u1 = h2v4[(size_t)s1 * 8 + cg];
        v2f wv0 = {w_0, w_0}, wv1 = {w_1, w_1};
        v2f t;
        t.x = bflo(u0.x); t.y = bfhi(u0.x); acc[0] += wv0 * t;
        t.x = bflo(u0.y); t.y = bfhi(u0.y); acc[1] += wv0 * t;
        t.x = bflo(u0.z); t.y = bfhi(u0.z); acc[2] += wv0 * t;
        t.x = bflo(u0.w); t.y = bfhi(u0.w); acc[3] += wv0 * t;
        t.x = bflo(u1.x); t.y = bfhi(u1.x); acc[0] += wv1 * t;
        t.x = bflo(u1.y); t.y = bfhi(u1.y); acc[1] += wv1 * t;
        t.x = bflo(u1.z); t.y = bfhi(u1.z); acc[2] += wv1 * t;
        t.x = bflo(u1.w); t.y = bfhi(u1.w); acc[3] += wv1 * t;
    }
    for (; b + 8 <= mcount; b += 8) {
        int i0 = b + sub;
        int s0 = __shfl(srcReg, i0);
        float w_0 = __shfl(wReg, i0);
        uint4 u0 = h2v4[(size_t)s0 * 8 + cg];
        v2f wv0 = {w_0, w_0};
        v2f t;
        t.x = bflo(u0.x); t.y = bfhi(u0.x); acc[0] += wv0 * t;
        t.x = bflo(u0.y); t.y = bfhi(u0.y); acc[1] += wv0 * t;
        t.x = bflo(u0.z); t.y = bfhi(u0.z); acc[2] += wv0 * t;
        t.x = bflo(u0.w); t.y = bfhi(u0.w); acc[3] += wv0 * t;
    }
    if (b < mcount) {
        int rem = mcount - b;
        int i0 = b + sub;
        int ic = min(i0, mcount - 1);
        int s0 = __shfl(srcReg, ic);
        float w_0 = __shfl(wReg, ic);
        if (sub < rem) {
            uint4 u0 = h2v4[(size_t)s0 * 8 + cg];
            v2f wv0 = {w_0, w_0};
            v2f t;
            t.x = bflo(u0.x); t.y = bfhi(u0.x); acc[0] += wv0 * t;
            t.x = bflo(u0.y); t.y = bfhi(u0.y); acc[1] += wv0 * t;
            t.x = bflo(u0.z); t.y = bfhi(u0.z); acc[2] += wv0 * t;
            t.x = bflo(u0.w); t.y = bfhi(u0.w); acc[3] += wv0 * t;
        }
    }
}

__global__ void __launch_bounds__(256)
agg2_kernel(const int* __restrict__ csr, const int* __restrict__ indptr,
            const int* __restrict__ counts, const float* __restrict__ as2,
            const float* __restrict__ ad2, const unsigned short* __restrict__ h2b,
            const float* __restrict__ b2, float* __restrict__ out, int N) {
    int lane = threadIdx.x & 63;
    int n = blockIdx.x * 4 + (threadIdx.x >> 6);
    if (n >= N) return;
    int start = indptr[n];
    int cnt = counts[n];
    float ad = ad2[n];

    int src0 = 0;
    float e0 = -1e30f;
    if (lane < cnt) {
        src0 = csr[start + lane];
        e0 = leaky(as2[src0] + ad);
    }
    float m = e0;
#pragma unroll
    for (int off = 32; off >= 1; off >>= 1) m = fmaxf(m, __shfl_xor(m, off));
    if (cnt > 64) {
        for (int base = 64; base < cnt; base += 64) {
            float e = -1e30f;
            if (base + lane < cnt) e = leaky(as2[csr[start + base + lane]] + ad);
#pragma unroll
            for (int off = 32; off >= 1; off >>= 1) e = fmaxf(e, __shfl_xor(e, off));
            m = fmaxf(m, e);
        }
    }
    float p0 = __expf(e0 - m);
    float l = p0;
#pragma unroll
    for (int off = 32; off >= 1; off >>= 1) l += __shfl_xor(l, off);
    if (cnt > 64) {
        for (int base = 64; base < cnt; base += 64) {
            float p = 0.f;
            if (base + lane < cnt) p = __expf(leaky(as2[csr[start + base + lane]] + ad) - m);
#pragma unroll
            for (int off = 32; off >= 1; off >>= 1) p += __shfl_xor(p, off);
            l += p;
        }
    }
    float li = 1.f / l;
    float w0 = p0 * li;

    int sub = lane >> 3;   // edge within 8-group
    int cg = lane & 7;     // channel group (8 ch each)
    const uint4* h2v4 = (const uint4*)h2b;
    v2f acc[4];
    acc[0] = acc[1] = acc[2] = acc[3] = (v2f){0.f, 0.f};
    accum2(src0, w0, min(cnt, 64), h2v4, sub, cg, acc);
    if (cnt > 64) {
        for (int base = 64; base < cnt; base += 64) {
            int srcc = 0;
            float wc = 0.f;
            if (base + lane < cnt) {
                srcc = csr[start + base + lane];
                wc = __expf(leaky(as2[srcc] + ad) - m) * li;
            }
            accum2(srcc, wc, min(cnt - base, 64), h2v4, sub, cg, acc);
        }
    }
#pragma unroll
    for (int i = 0; i < 4; i++) {
        acc[i].x += __shfl_xor(acc[i].x, 8);
        acc[i].x += __shfl_xor(acc[i].x, 16);
        acc[i].x += __shfl_xor(acc[i].x, 32);
        acc[i].y += __shfl_xor(acc[i].y, 8);
        acc[i].y += __shfl_xor(acc[i].y, 16);
        acc[i].y += __shfl_xor(acc[i].y, 32);
    }
    if (lane < 8) {
        const float4* b4 = (const float4*)b2;
        float4 ba = b4[cg * 2], bb = b4[cg * 2 + 1];
        float4 o0, o1;
        o0.x = acc[0].x + ba.x; o0.y = acc[0].y + ba.y;
        o0.z = acc[1].x + ba.z; o0.w = acc[1].y + ba.w;
        o1.x = acc[2].x + bb.x; o1.y = acc[2].y + bb.y;
        o1.z = acc[3].x + bb.z; o1.w = acc[3].y + bb.w;
        float4* orow = (float4*)&out[(size_t)n * 64 + cg * 8];
        orow[0] = o0;
        orow[1] = o1;
    }
}

// ---------------- launcher ----------------

extern "C" void kernel_launch(void* const* d_in, const int* in_sizes, int n_in,
                              void* d_out, int out_size, void* d_ws, size_t ws_size,
                              hipStream_t stream) {
    const int*   xidx = (const int*)d_in[0];
    const int*   ei   = (const int*)d_in[1];
    const float* emb  = (const float*)d_in[2];
    const float* W1   = (const float*)d_in[3];
    const float* a_s1 = (const float*)d_in[4];
    const float* a_d1 = (const float*)d_in[5];
    const float* b1   = (const float*)d_in[6];
    const float* W2   = (const float*)d_in[7];
    const float* a_s2 = (const float*)d_in[8];
    const float* a_d2 = (const float*)d_in[9];
    const float* b2   = (const float*)d_in[10];
    float* out = (float*)d_out;

    const int N  = in_sizes[0];
    const int E  = in_sizes[1] / 2;
    const int E2 = E + N;
    const int K  = (N + 255) >> BK_SHIFT;   // 391 buckets for N=100000

    // workspace layout
    int* ws_i    = (int*)d_ws;
    int* counts  = ws_i;                       // N
    int* indptr  = ws_i + N;                   // N
    int* bcounts = ws_i + 2 * (size_t)N;       // 512
    int* bbase   = ws_i + 2 * (size_t)N + 512; // 513
    int* bcursor = ws_i + 2 * (size_t)N + 1032;// 512
    int* csr     = ws_i + 2 * (size_t)N + 1544;// E2
    size_t fbase = ((size_t)(2 * (size_t)N + 1544 + E2) + 3) & ~(size_t)3;
    float* ws_f = (float*)d_ws;
    unsigned short* h1b = (unsigned short*)(ws_f + fbase);             // N*128 bf16
    unsigned short* x1b = (unsigned short*)(ws_f + fbase + (size_t)N * 64);  // N*128 bf16
    float* as1 = ws_f + fbase + (size_t)N * 128;                       // N*4
    float* ad1 = as1 + (size_t)N * 4;                                  // N*4
    unsigned short* h2b = h1b;            // alias: h1b dead after agg1 (N*64 bf16)
    float* as2 = as1;                     // alias
    float* ad2 = ad1;
    unsigned int* bedges = (unsigned int*)x1b;  // alias: dead before agg1 writes x1b

    // CSR build: dst-radix partition
    int nchunks = (E2 + 4095) / 4096;
    zero_kernel<<<(K + 255) / 256, 256, 0, stream>>>(bcounts, K);
    bcount_kernel<<<nchunks, 256, 0, stream>>>(ei, E, E2, K, bcounts);
    bscan_kernel<<<1, 512, 0, stream>>>(bcounts, K, bbase, bcursor);
    bscatter_kernel<<<nchunks, 256, 0, stream>>>(ei, E, E2, K, bcursor, bedges);
    bcsr_kernel<<<K, 256, 0, stream>>>(bedges, bbase, N, counts, indptr, csr);

    // Layer 1 (gemm1 fuses alpha1 + bf16 h1)
    {
        dim3 g((N + 63) / 64, 2);
        gemm1_kernel<<<g, 256, 0, stream>>>(emb, xidx, W1, h1b, a_s1, a_d1, as1, ad1, N);
    }
    agg1_kernel<<<(N + 3) / 4, 256, 0, stream>>>(csr, indptr, counts, as1, ad1, h1b, b1, x1b, N);

    // Layer 2 (gemm2 fuses alpha2 + bf16 h2, reads bf16 x1)
    gemm2_kernel<<<(N + 63) / 64, 256, 0, stream>>>(x1b, W2, h2b, a_s2, a_d2, as2, ad2, N);
    agg2_kernel<<<(N + 3) / 4, 256, 0, stream>>>(csr, indptr, counts, as2, ad2, h2b, b2, out, N);
}